// Round 7
// baseline (644.344 us; speedup 1.0000x reference)
//
#include <hip/hip_runtime.h>
#include <math.h>

#define DD 32
#define DD4 128
#define TPB 256
#define LDSCAP 6144
#define CANDCAP 2048

// ---------- sortable key mappings ----------
__device__ __forceinline__ unsigned long long dsort_key(double x) {
  unsigned long long b = (unsigned long long)__double_as_longlong(x);
  return (b & 0x8000000000000000ull) ? ~b : (b | 0x8000000000000000ull);
}
__device__ __forceinline__ double dunsort_key(unsigned long long k) {
  unsigned long long b = (k & 0x8000000000000000ull) ? (k ^ 0x8000000000000000ull) : ~k;
  return __longlong_as_double((long long)b);
}
__device__ __forceinline__ unsigned int fsort_key(float x) {
  unsigned int b = __float_as_uint(x);
  return (b & 0x80000000u) ? ~b : (b | 0x80000000u);
}
__device__ __forceinline__ float funsort_key(unsigned int k) {
  unsigned int b = (k & 0x80000000u) ? (k ^ 0x80000000u) : ~k;
  return __uint_as_float(b);
}

// inclusive scan over 256 threads (4 waves of 64). All 256 threads must call.
// Contains 2 barriers; wsum must be a 4-int LDS buffer.
__device__ __forceinline__ int block_iscan256(int x, int* wsum) {
  const int lane = threadIdx.x & 63, w = threadIdx.x >> 6;
#pragma unroll
  for (int o = 1; o < 64; o <<= 1) {
    int y = __shfl_up(x, o, 64);
    if (lane >= o) x += y;
  }
  if (lane == 63) wsum[w] = x;
  __syncthreads();
  int add = 0;
#pragma unroll
  for (int i = 0; i < 4; ++i) add += (i < w) ? wsum[i] : 0;
  __syncthreads();  // allow wsum reuse by a later call
  return x + add;
}

// ---------- K1: M = Wq^T Wk (f64 + f32 mirror) ----------
__global__ __launch_bounds__(TPB) void k_precompute_M(
    const float* __restrict__ Wq, const float* __restrict__ Wk,
    double* __restrict__ M64, float* __restrict__ M32) {
  int t = blockIdx.x * blockDim.x + threadIdx.x;  // 16384 threads
  int i = t >> 7, j = t & 127;
  double acc = 0.0;
  for (int k = 0; k < DD4; ++k)
    acc += (double)Wq[k * DD4 + i] * (double)Wk[k * DD4 + j];
  M64[i * DD4 + j] = acc;
  M32[i * DD4 + j] = (float)acc;
}

// ---------- K1b: symmetrized G22: S[i][j] = G22ij+G22ji (j>i), diag (j==i), 0 (j<i) ----------
__global__ __launch_bounds__(TPB) void k_sym22(
    const double* __restrict__ M64, double* __restrict__ S64, float* __restrict__ S32) {
  int i = blockIdx.x * blockDim.x + threadIdx.x;  // 1024 threads
  int r = i >> 5, c = i & 31;
  double g  = M64[(32 + r) * DD4 + 32 + c];
  double gt = M64[(32 + c) * DD4 + 32 + r];
  double s = (c > r) ? (g + gt) : ((c == r) ? g : 0.0);
  S64[i] = s;
  S32[i] = (float)s;
}

// ---------- K2: per-query precompute p (64), pD (32), c (scalar) ----------
__global__ __launch_bounds__(64) void k_per_query(
    const double* __restrict__ M64,
    const float* __restrict__ qemb, const float* __restrict__ remb,
    double* __restrict__ p64, double* __restrict__ pD64, double* __restrict__ c64,
    float* __restrict__ p32, float* __restrict__ pD32, float* __restrict__ c32) {
  int q = blockIdx.x;
  int l = threadIdx.x;  // 64 threads = 1 wave
  __shared__ double qr[64];
  qr[l] = (l < DD) ? (double)qemb[q * DD + l] : (double)remb[q * DD + (l - DD)];
  __syncthreads();
  double a = 0.0;
  for (int j = 0; j < 64; ++j) a += M64[l * DD4 + 64 + j] * qr[j];
  double ct = 0.0;
  for (int j = 0; j < 64; ++j) ct += M64[(64 + j) * DD4 + l] * qr[j];
  if (l >= DD) a += ct;  // fold rel-part of z^T C x into p (x==y there)
  p64[q * 64 + l] = a;
  p32[q * 64 + l] = (float)a;
  if (l < DD) {
    pD64[q * DD + l] = ct;
    pD32[q * DD + l] = (float)ct;
  }
  double a3 = 0.0;
  for (int j = 0; j < 64; ++j) a3 += M64[(64 + l) * DD4 + 64 + j] * qr[j];
  a3 *= qr[l];
  for (int o = 32; o; o >>= 1) a3 += __shfl_xor(a3, o);
  if (l == 0) { c64[q] = a3; c32[q] = (float)a3; }
}

// ---------- K3: per-node precompute t = G11 h, u = G12^T h, v = G21 h ----------
// Thread-per-node, h in registers (compile-time indices). G is wave-uniform and
// read DIRECTLY from Mmat with uniform indices -> scalar loads into SGPRs
// (v_fma takes one SGPR operand) -> zero LDS/shfl in the compute loop.
// Outputs go through an LDS transpose tile so global stores are coalesced.
// MIX: h = 0.8*agg + 0.2*reprIn, also written (coalesced) to reprOut.
#define G_T(c) Mmat[(c) * DD4 + j]
#define G_U(c) Mmat[j * DD4 + 32 + (c)]
#define G_V(c) Mmat[(32 + (c)) * DD4 + j]

#define NP_TILE(GEXPR)                                                          \
  for (int tt = 0; tt < 4; ++tt) {                                              \
    T a0=(T)0,a1=(T)0,a2=(T)0,a3=(T)0,a4=(T)0,a5=(T)0,a6=(T)0,a7=(T)0;          \
    const int c0 = tt * 8;                                                      \
    _Pragma("unroll")                                                           \
    for (int j = 0; j < 32; ++j) {                                              \
      const T hj = hh[j];                                                       \
      a0 += (GEXPR(c0 + 0)) * hj; a1 += (GEXPR(c0 + 1)) * hj;                   \
      a2 += (GEXPR(c0 + 2)) * hj; a3 += (GEXPR(c0 + 3)) * hj;                   \
      a4 += (GEXPR(c0 + 4)) * hj; a5 += (GEXPR(c0 + 5)) * hj;                   \
      a6 += (GEXPR(c0 + 6)) * hj; a7 += (GEXPR(c0 + 7)) * hj;                   \
    }                                                                           \
    xq[tid * 9 + tt * 2]     = make_float4((float)a0,(float)a1,(float)a2,(float)a3); \
    xq[tid * 9 + tt * 2 + 1] = make_float4((float)a4,(float)a5,(float)a6,(float)a7); \
  }

#define NP_STORE(dst)                                                           \
  __syncthreads();                                                              \
  {                                                                             \
    float4* go = (float4*)(dst) + (size_t)nbase * 8;                            \
    _Pragma("unroll")                                                           \
    for (int k = 0; k < 8; ++k) {                                               \
      int f = k * TPB + tid;                                                    \
      if ((f >> 3) < nlim) go[f] = xq[(f >> 3) * 9 + (f & 7)];                  \
    }                                                                           \
  }                                                                             \
  __syncthreads();

template <typename T, bool MIX>
__global__ __launch_bounds__(TPB) void k_node_pre(
    const T* __restrict__ Mmat, const float* __restrict__ reprIn,
    const float* __restrict__ aggIn, float* __restrict__ reprOut,
    float* __restrict__ t, float* __restrict__ u, float* __restrict__ v, int N_) {
  __shared__ float xp[TPB * 36];   // stride 9 float4s -> bank-balanced
  float4* xq = (float4*)xp;
  const int tid = threadIdx.x;
  const int nbase = blockIdx.x * TPB;
  const int n = nbase + tid;
  const int nlim = min(TPB, N_ - nbase);
  const bool valid = tid < nlim;
  T hh[32];
  if (valid) {
    const float4* h4 = (const float4*)reprIn + (size_t)n * 8;
#pragma unroll
    for (int jq = 0; jq < 8; ++jq) {
      float4 x = h4[jq];
      if constexpr (MIX) {
        const float4 a = ((const float4*)aggIn)[(size_t)n * 8 + jq];
        x = make_float4(0.8f * a.x + 0.2f * x.x, 0.8f * a.y + 0.2f * x.y,
                        0.8f * a.z + 0.2f * x.z, 0.8f * a.w + 0.2f * x.w);
        xq[tid * 9 + jq] = x;   // stage mixed h for coalesced reprOut store
      }
      hh[4 * jq]     = (T)x.x; hh[4 * jq + 1] = (T)x.y;
      hh[4 * jq + 2] = (T)x.z; hh[4 * jq + 3] = (T)x.w;
    }
  } else {
#pragma unroll
    for (int j = 0; j < 32; ++j) hh[j] = (T)0;
  }
  if constexpr (MIX) {
    NP_STORE(reprOut)
  }
  NP_TILE(G_T)
  NP_STORE(t)
  NP_TILE(G_U)
  NP_STORE(u)
  NP_TILE(G_V)
  NP_STORE(v)
}

// ---------- K4a: per-edge rel-quadratic: quad = c_q + rel·p_rel + sum_{i<=j} S_ij x_i x_j ----------
// S is wave-uniform -> read directly (scalar loads), no LDS staging. Fully
// unrolled (compile-time rl[] indices only).
template <typename T>
__global__ __launch_bounds__(TPB) void k_quad(
    const T* __restrict__ Smat,
    const float* __restrict__ rel, const int* __restrict__ eg,
    const T* __restrict__ pq, const T* __restrict__ cq,
    T* __restrict__ quad, int E) {
  const int e = blockIdx.x * TPB + threadIdx.x;
  if (e >= E) return;
  const int q = eg[e];
  T rl[32];
  {
    const float4* r4 = (const float4*)rel + (size_t)e * 8;
#pragma unroll
    for (int j = 0; j < 8; ++j) {
      float4 x = r4[j];
      rl[4 * j] = (T)x.x; rl[4 * j + 1] = (T)x.y;
      rl[4 * j + 2] = (T)x.z; rl[4 * j + 3] = (T)x.w;
    }
  }
  const T* prow = pq + (size_t)q * 64 + 32;
  T lin0 = (T)0, lin1 = (T)0;
#pragma unroll
  for (int i = 0; i < 32; i += 2) {
    lin0 += prow[i] * rl[i];
    lin1 += prow[i + 1] * rl[i + 1];
  }
  T a0 = cq[q] + lin0, a1 = lin1, a2 = (T)0, a3 = (T)0;
#pragma unroll
  for (int i = 0; i < 32; ++i) {
    T r0 = Smat[i * 32 + i] * rl[i];
    T r1 = (T)0;
#pragma unroll
    for (int j = i + 1; j < 32; ++j) {
      if ((j - i) & 1) r1 += Smat[i * 32 + j] * rl[j];
      else             r0 += Smat[i * 32 + j] * rl[j];
    }
    T rr = (r0 + r1) * rl[i];
    if ((i & 3) == 0) a0 += rr;
    else if ((i & 3) == 1) a1 += rr;
    else if ((i & 3) == 2) a2 += rr;
    else a3 += rr;
  }
  quad[e] = (a0 + a1) + (a2 + a3);
}

// ---------- K4b: 8-lanes-per-edge gather dots + reduce + atomicMax ----------
template <typename T>
__global__ __launch_bounds__(TPB) void k_edge_dots(
    const float* __restrict__ repr, const float* __restrict__ rel,
    const int* __restrict__ src, const int* __restrict__ dst, const int* __restrict__ eg,
    const float* __restrict__ tvec, const float* __restrict__ uvec, const float* __restrict__ vvec,
    const T* __restrict__ pq, const T* __restrict__ pDq, const T* __restrict__ quad,
    T* __restrict__ logits, void* __restrict__ mkey, int E) {
  const long long t = (long long)blockIdx.x * TPB + threadIdx.x;
  const int e = (int)(t >> 3), part = (int)(t & 7);
  if (e >= E) return;
  const int s = src[e], d = dst[e], q = eg[e];
  const float4 hs = ((const float4*)repr)[(size_t)s * 8 + part];
  const float4 td = ((const float4*)tvec)[(size_t)d * 8 + part];
  const float4 hd = ((const float4*)repr)[(size_t)d * 8 + part];
  const float4 rl = ((const float4*)rel)[(size_t)e * 8 + part];
  const float4 us = ((const float4*)uvec)[(size_t)s * 8 + part];
  const float4 vd = ((const float4*)vvec)[(size_t)d * 8 + part];
  const T* p  = pq  + (size_t)q * 64 + part * 4;
  const T* pD = pDq + (size_t)q * DD + part * 4;
  T a = (T)hs.x * ((T)td.x + p[0]) + (T)hs.y * ((T)td.y + p[1]) +
        (T)hs.z * ((T)td.z + p[2]) + (T)hs.w * ((T)td.w + p[3]);
  a += (T)hd.x * pD[0] + (T)hd.y * pD[1] + (T)hd.z * pD[2] + (T)hd.w * pD[3];
  a += (T)rl.x * (T)(us.x + vd.x) + (T)rl.y * (T)(us.y + vd.y) +
       (T)rl.z * (T)(us.z + vd.z) + (T)rl.w * (T)(us.w + vd.w);
  a += __shfl_xor(a, 1);
  a += __shfl_xor(a, 2);
  a += __shfl_xor(a, 4);
  if (part == 0) {
    a += quad[e];
    logits[e] = a;
    if constexpr (sizeof(T) == 8) {
      atomicMax((unsigned long long*)mkey + s, dsort_key((double)a));
    } else {
      atomicMax((unsigned int*)mkey + s, fsort_key((float)a));
    }
  }
}

// ---------- K5: ex = exp(l - m[src]); s[src] += ex (in-place) ----------
__global__ __launch_bounds__(TPB) void k_expsum64(
    double* __restrict__ io, const unsigned long long* __restrict__ mkey,
    const int* __restrict__ src, double* __restrict__ ssum, int E) {
  int e = blockIdx.x * blockDim.x + threadIdx.x;
  if (e >= E) return;
  int s = src[e];
  double ex = exp(io[e] - dunsort_key(mkey[s]));
  io[e] = ex;
  atomicAdd(&ssum[s], ex);
}
// layer-0 variant: also builds the dst histogram for the CSR (old k_hist fused)
__global__ __launch_bounds__(TPB) void k_expsum32h(
    float* __restrict__ io, const unsigned int* __restrict__ mkey,
    const int* __restrict__ src, const int* __restrict__ dst,
    float* __restrict__ ssum, int* __restrict__ cnt, int E) {
  int e = blockIdx.x * blockDim.x + threadIdx.x;
  if (e >= E) return;
  int s = src[e];
  float ex = expf(io[e] - funsort_key(mkey[s]));
  io[e] = ex;
  atomicAdd(&ssum[s], ex);
  atomicAdd(&cnt[dst[e]], 1);
}

// ---------- K6: w1 = ex/s; target key; ALSO qoff[] (old k_qoff fused) ----------
__global__ __launch_bounds__(TPB) void k_weights_target(
    const double* __restrict__ ex, const double* __restrict__ ssum,
    const int* __restrict__ src, const float* __restrict__ score,
    const int* __restrict__ eg, int* __restrict__ qoff,
    float* __restrict__ w1f, unsigned int* __restrict__ tkey, int E, int Q) {
  int e = blockIdx.x * blockDim.x + threadIdx.x;
  if (e >= E) return;
  int s = src[e];
  double w = ex[e] / ssum[s];
  float wf = (float)w;
  w1f[e] = wf;
  float tgt = wf * score[s];
  tkey[e] = fsort_key(tgt);
  // qoff[v] = first edge index with eg >= v (eg sorted)
  int cur = eg[e];
  int prev = (e == 0) ? -1 : eg[e - 1];
  for (int v = prev + 1; v <= cur; ++v) qoff[v] = e;
  if (e == E - 1) {
    for (int v = cur + 1; v <= Q; ++v) qoff[v] = E;
  }
}

// ---------- K7: per-query top-k via radix select ----------
// Parallel digit select (shfl suffix-scan) + candidate compaction after pass 0.
__global__ __launch_bounds__(TPB) void k_topk(
    const unsigned int* __restrict__ tkey, const float* __restrict__ w1f,
    const int* __restrict__ qoff, const int* __restrict__ maxe,
    float* __restrict__ w1p, int E) {
  __shared__ unsigned int keys[LDSCAP];
  __shared__ int hist[256];
  __shared__ unsigned short cand[CANDCAP];
  __shared__ int wsum[4];
  __shared__ int sh_cnt;
  __shared__ unsigned int sh_prefix;
  __shared__ int sh_need;
  const int q = blockIdx.x;
  const int s = qoff[q], e2 = qoff[q + 1];
  const int n = e2 - s;
  const int K = maxe[0];
  if (n <= K) {
    for (int i = s + threadIdx.x; i < e2; i += TPB) w1p[i] = w1f[i];
    return;
  }
  const bool useLds = (n <= LDSCAP);
  if (useLds) {
    for (int i = threadIdx.x; i < n; i += TPB) keys[i] = tkey[s + i];
  }
  // ---- pass 0: histogram of top byte ----
  hist[threadIdx.x] = 0;
  __syncthreads();
  for (int i = threadIdx.x; i < n; i += TPB) {
    unsigned int k = useLds ? keys[i] : tkey[s + i];
    atomicAdd(&hist[k >> 24], 1);
  }
  __syncthreads();
  int need = K;
  {
    int h = hist[255 - threadIdx.x];
    int incl = block_iscan256(h, wsum);     // suffix sum (descending digit)
    int excl = incl - h;
    if (incl >= need && excl < need) {
      sh_prefix = (unsigned int)(255 - threadIdx.x) << 24;
      sh_need = need - excl;
    }
  }
  __syncthreads();
  unsigned int prefix = sh_prefix;
  need = sh_need;
  // ---- compact candidates matching the leading digit ----
  const int cnt0 = hist[prefix >> 24];
  const bool compact = useLds && (cnt0 <= CANDCAP);
  if (threadIdx.x == 0) sh_cnt = 0;
  __syncthreads();
  if (compact) {
    const unsigned int d0 = prefix >> 24;
    for (int i = threadIdx.x; i < n; i += TPB) {
      if ((keys[i] >> 24) == d0) {
        int p = atomicAdd(&sh_cnt, 1);
        cand[p] = (unsigned short)i;
      }
    }
  }
  __syncthreads();
  const int ncand = compact ? sh_cnt : 0;
  // ---- passes 1..3 ----
  for (int pass = 1; pass < 4; ++pass) {
    const int shift = 24 - 8 * pass;
    const unsigned int himask = 0xFFFFFFFFu << (shift + 8);
    hist[threadIdx.x] = 0;
    __syncthreads();
    if (compact) {
      for (int ci = threadIdx.x; ci < ncand; ci += TPB) {
        unsigned int k = keys[cand[ci]];
        if ((k & himask) == prefix) atomicAdd(&hist[(k >> shift) & 255], 1);
      }
    } else {
      for (int i = threadIdx.x; i < n; i += TPB) {
        unsigned int k = useLds ? keys[i] : tkey[s + i];
        if ((k & himask) == prefix) atomicAdd(&hist[(k >> shift) & 255], 1);
      }
    }
    __syncthreads();
    int h = hist[255 - threadIdx.x];
    int incl = block_iscan256(h, wsum);
    int excl = incl - h;
    if (incl >= need && excl < need) {
      sh_prefix = prefix | ((unsigned int)(255 - threadIdx.x) << shift);
      sh_need = need - excl;
    }
    __syncthreads();
    prefix = sh_prefix;
    need = sh_need;
    __syncthreads();
  }
  const unsigned int kth = prefix;   // exact kth-largest key
  const int r = need;                // # of kth-valued ties to keep (index order)
  // ---- tie ranks via contiguous chunks + shfl block scan ----
  const int C = (n + TPB - 1) / TPB;
  const int b0 = min(threadIdx.x * C, n);
  const int b1 = min(b0 + C, n);
  int myt = 0;
  for (int i = b0; i < b1; ++i) {
    unsigned int k = useLds ? keys[i] : tkey[s + i];
    myt += (k == kth) ? 1 : 0;
  }
  int tincl = block_iscan256(myt, wsum);
  int tiepre = tincl - myt;  // exclusive prefix of ties before my chunk
  for (int i = b0; i < b1; ++i) {
    unsigned int k = useLds ? keys[i] : tkey[s + i];
    float v = 0.f;
    if (k > kth) {
      v = w1f[s + i];
    } else if (k == kth) {
      if (tiepre < r) v = w1f[s + i];
      ++tiepre;
    }
    w1p[s + i] = v;
  }
}

// ---------- K8: layer-1 scatter: score + repr agg over kept edges (sparse) ----------
__global__ __launch_bounds__(TPB) void k_apply1(
    const float* __restrict__ w1p, const int* __restrict__ src, const int* __restrict__ dst,
    const float* __restrict__ repr0, const float* __restrict__ score,
    float* __restrict__ agg, float* __restrict__ score_out, int E) {
  int t = blockIdx.x * blockDim.x + threadIdx.x;
  int e = t >> 3, part = t & 7;
  if (e >= E) return;
  float w = w1p[e];
  if (w == 0.f) return;
  int sv = src[e], dv = dst[e];
  const float4 rv = ((const float4*)repr0)[sv * 8 + part];
  float* ap = agg + (size_t)dv * DD + part * 4;
  atomicAdd(ap + 0, w * rv.x);
  atomicAdd(ap + 1, w * rv.y);
  atomicAdd(ap + 2, w * rv.z);
  atomicAdd(ap + 3, w * rv.w);
  if (part == 0) atomicAdd(score_out + dv, w * score[sv]);
}

// ---------- CSR scans ----------
#define SCHUNK 1024
__global__ __launch_bounds__(TPB) void k_scan1(
    const int* __restrict__ cnt, int* __restrict__ off, int* __restrict__ bsum, int N_) {
  __shared__ int sd[TPB];
  const int b = blockIdx.x, t = threadIdx.x;
  const int base = b * SCHUNK + t * 4;
  int v[4];
  int s4 = 0;
#pragma unroll
  for (int k = 0; k < 4; ++k) {
    v[k] = (base + k < N_) ? cnt[base + k] : 0;
    s4 += v[k];
  }
  sd[t] = s4;
  __syncthreads();
  for (int o = 1; o < TPB; o <<= 1) {
    int x = (t >= o) ? sd[t - o] : 0;
    __syncthreads();
    sd[t] += x;
    __syncthreads();
  }
  int excl = sd[t] - s4;
  if (t == TPB - 1) bsum[b] = sd[t];
  int run = excl;
#pragma unroll
  for (int k = 0; k < 4; ++k) {
    if (base + k < N_) { off[base + k] = run; run += v[k]; }
  }
}

// parallel exclusive scan over bsum (nblk <= 256 fast path; serial fallback)
__global__ __launch_bounds__(TPB) void k_scan2(
    int* __restrict__ bsum, int* __restrict__ off, int nblk, int N_, int E) {
  __shared__ int wsum[4];
  if (nblk <= TPB) {
    int t = threadIdx.x;
    int x = (t < nblk) ? bsum[t] : 0;
    int orig = x;
    const int lane = t & 63, w = t >> 6;
#pragma unroll
    for (int o = 1; o < 64; o <<= 1) {
      int y = __shfl_up(x, o, 64);
      if (lane >= o) x += y;
    }
    if (lane == 63) wsum[w] = x;
    __syncthreads();
    int add = 0;
#pragma unroll
    for (int i = 0; i < 4; ++i) add += (i < w) ? wsum[i] : 0;
    x += add;
    if (t < nblk) bsum[t] = x - orig;   // exclusive
    if (t == 0) off[N_] = E;
  } else {
    if (threadIdx.x != 0) return;
    int run = 0;
    for (int i = 0; i < nblk; ++i) { int tmp = bsum[i]; bsum[i] = run; run += tmp; }
    off[N_] = E;
  }
}

__global__ __launch_bounds__(TPB) void k_scan3(
    int* __restrict__ off, const int* __restrict__ bsum, int* __restrict__ cursor, int N_) {
  int i = blockIdx.x * blockDim.x + threadIdx.x;
  if (i >= N_) return;
  int v = off[i] + bsum[i >> 10];
  off[i] = v;
  cursor[i] = v;
}

// ---------- K12a: scatter packed {w, src} into dst-CSR order ----------
__global__ __launch_bounds__(TPB) void k_scatter0(
    const float* __restrict__ ex, const float* __restrict__ ssum,
    const int* __restrict__ src, const int* __restrict__ dst,
    int* __restrict__ cursor, float2* __restrict__ pk, int E) {
  int e = blockIdx.x * blockDim.x + threadIdx.x;
  if (e >= E) return;
  int s = src[e];
  float w = ex[e] / ssum[s];
  int pos = atomicAdd(&cursor[dst[e]], 1);
  pk[pos] = make_float2(w, __int_as_float(s));
}

// ---------- K12b: gather per dst node + fused mix + Linear + LeakyReLU ----------
// MLP rewrite: load up to 32 pk entries lane-parallel (one coalesced load),
// broadcast (w,s) via shfl, then the repr1 row-gathers are address-independent
// and pipeline (the old version serialized pk[j] -> s -> gather per edge).
// Accumulation order (ascending j) is unchanged -> bit-identical output.
__global__ __launch_bounds__(TPB) void k_gather_final(
    const float2* __restrict__ pk, const int* __restrict__ off,
    const float* __restrict__ repr1,
    const float* __restrict__ Wlin, const float* __restrict__ blin,
    float* __restrict__ out_repr, int N_) {
  __shared__ float WsT[DD * DD];   // WsT[j*32+i] = Wlin[i*32+j]
  __shared__ float bs[DD];
  for (int i = threadIdx.x; i < DD * DD; i += TPB) {
    int r = i >> 5, c = i & 31;
    WsT[c * DD + r] = Wlin[i];
  }
  if (threadIdx.x < DD) bs[threadIdx.x] = blin[threadIdx.x];
  __syncthreads();
  const int n = blockIdx.x * 8 + (threadIdx.x >> 5);  // node
  const int c = threadIdx.x & 31;                     // component
  if (n >= N_) return;
  float acc = 0.f;
  const int j0 = off[n], j1 = off[n + 1];
  for (int base = j0; base < j1; base += 32) {
    const int m = min(32, j1 - base);
    float2 p = (base + c < j1) ? pk[base + c] : make_float2(0.f, 0.f);
    for (int j = 0; j < m; ++j) {
      const float wj = __shfl(p.x, j, 32);
      const int sj = __float_as_int(__shfl(p.y, j, 32));
      acc += wj * repr1[(size_t)sj * DD + c];
    }
  }
  float mix = 0.8f * acc + 0.2f * repr1[(size_t)n * DD + c];
  float o = bs[c];
#pragma unroll 8
  for (int j = 0; j < DD; ++j) {
    float mj = __shfl(mix, j, 32);
    o += WsT[j * DD + c] * mj;
  }
  out_repr[(size_t)n * DD + c] = (o >= 0.f) ? o : 0.01f * o;
}

extern "C" void kernel_launch(void* const* d_in, const int* in_sizes, int n_in,
                              void* d_out, int out_size, void* d_ws, size_t ws_size,
                              hipStream_t stream) {
  (void)n_in; (void)out_size; (void)ws_size;
  const float* score = (const float*)d_in[0];
  const float* nrepr = (const float*)d_in[1];
  const int*   eg0   = (const int*)d_in[2];
  const int*   src0  = (const int*)d_in[3];
  const int*   dst0  = (const int*)d_in[4];
  const float* rel0  = (const float*)d_in[5];
  const int*   eg1   = (const int*)d_in[6];
  const int*   src1  = (const int*)d_in[7];
  const int*   dst1  = (const int*)d_in[8];
  const float* rel1  = (const float*)d_in[9];
  const float* qemb  = (const float*)d_in[10];
  const float* remb  = (const float*)d_in[11];
  const float* Wq    = (const float*)d_in[12];
  const float* Wk    = (const float*)d_in[13];
  const float* Wlin  = (const float*)d_in[14];
  const float* blin  = (const float*)d_in[15];
  const int*   maxe  = (const int*)d_in[16];

  const int N_ = in_sizes[0];
  const int E_ = in_sizes[2];
  const int Q_ = in_sizes[10] / DD;

  char* wsc = (char*)d_ws;
  size_t off = 0;
  auto alloc = [&](size_t bytes) -> void* {
    void* p = wsc + off;
    off += (bytes + 255) & ~(size_t)255;
    return p;
  };
  double* M64  = (double*)alloc((size_t)DD4 * DD4 * 8);
  float*  M32  = (float*)alloc((size_t)DD4 * DD4 * 4);
  double* S64  = (double*)alloc((size_t)DD * DD * 8);
  float*  S32  = (float*)alloc((size_t)DD * DD * 4);
  double* p64  = (double*)alloc((size_t)Q_ * 64 * 8);
  double* pD64 = (double*)alloc((size_t)Q_ * DD * 8);
  double* c64  = (double*)alloc((size_t)Q_ * 8);
  float*  p32  = (float*)alloc((size_t)Q_ * 64 * 4);
  float*  pD32 = (float*)alloc((size_t)Q_ * DD * 4);
  float*  c32  = (float*)alloc((size_t)Q_ * 4);
  int*    qoff = (int*)alloc((size_t)(Q_ + 2) * 4);
  double* lg1  = (double*)alloc((size_t)E_ * 8);
  double* qv64 = (double*)alloc((size_t)E_ * 8);   // per-edge rel-quadratic (reused as f32 for layer 0)
  float*  w1f  = (float*)alloc((size_t)E_ * 4);
  unsigned int* tkey = (unsigned int*)alloc((size_t)E_ * 4);
  float*  w1p  = (float*)alloc((size_t)E_ * 4);
  float*  lg0  = (float*)alloc((size_t)E_ * 4);
  float*  repr1 = (float*)alloc((size_t)N_ * DD * 4);
  float*  tvec = (float*)alloc((size_t)N_ * DD * 4);   // reused: node-pre, then CSR scratch
  float*  uvec = (float*)alloc((size_t)N_ * DD * 4);   // reused: then pk
  float*  vvec = (float*)alloc((size_t)N_ * DD * 4);
  // zero-initialized region (contiguous)
  size_t zstart = off;
  unsigned long long* mkey1 = (unsigned long long*)alloc((size_t)N_ * 8);
  double* s1   = (double*)alloc((size_t)N_ * 8);
  float*  agg  = (float*)alloc((size_t)N_ * DD * 4);
  unsigned int* mkey0 = (unsigned int*)alloc((size_t)N_ * 4);
  float*  s0   = (float*)alloc((size_t)N_ * 4);
  size_t zlen = off - zstart;

  float* qv32 = (float*)qv64;   // layer-0 reuse (layer-1 consumer already done)

  // CSR scratch aliases tvec/uvec (dead after k_edge_dots<float>).
  // NOTE padding: offcsr needs N+1 ints — cursor must start past offcsr[N].
  int* cnt    = (int*)tvec;                         // [0, N)
  int* offcsr = (int*)tvec + N_;                    // [N, 2N+1)  (N+1 ints!)
  int* cursor = (int*)tvec + 2 * (size_t)N_ + 64;   // padded past offcsr[N]
  int* bsum   = (int*)tvec + 3 * (size_t)N_ + 128;  // nblk ints
  float2* pk  = (float2*)uvec;                      // E float2 = 4 MB (uvec is 12.8 MB)

  float* out_score = (float*)d_out;
  float* out_repr  = out_score + N_;

  hipMemsetAsync(wsc + zstart, 0, zlen, stream);
  hipMemsetAsync(d_out, 0, (size_t)N_ * 4, stream);

  k_precompute_M<<<(DD4 * DD4) / TPB, TPB, 0, stream>>>(Wq, Wk, M64, M32);
  k_sym22<<<4, TPB, 0, stream>>>(M64, S64, S32);
  k_per_query<<<Q_, 64, 0, stream>>>(M64, qemb, remb, p64, pD64, c64, p32, pD32, c32);

  const int ngrid = (N_ + TPB - 1) / TPB;
  const int egrid = (E_ + TPB - 1) / TPB;
  const int dgrid = (int)(((size_t)E_ * 8 + TPB - 1) / TPB);

  // ---- layer 1 (f64 logits path, selection-critical) ----
  k_node_pre<double, false><<<ngrid, TPB, 0, stream>>>(M64, nrepr, nullptr, nullptr,
                                                       tvec, uvec, vvec, N_);
  k_quad<double><<<egrid, TPB, 0, stream>>>(S64, rel1, eg1, p64, c64, qv64, E_);
  k_edge_dots<double><<<dgrid, TPB, 0, stream>>>(nrepr, rel1, src1, dst1, eg1,
                                                 tvec, uvec, vvec, p64, pD64, qv64,
                                                 lg1, (void*)mkey1, E_);
  k_expsum64<<<egrid, TPB, 0, stream>>>(lg1, mkey1, src1, s1, E_);
  k_weights_target<<<egrid, TPB, 0, stream>>>(lg1, s1, src1, score, eg1, qoff,
                                              w1f, tkey, E_, Q_);
  k_topk<<<Q_, TPB, 0, stream>>>(tkey, w1f, qoff, maxe, w1p, E_);

  k_apply1<<<dgrid, TPB, 0, stream>>>(w1p, src1, dst1, nrepr, score, agg, out_score, E_);

  // ---- layer 0 (f32): node-pre fused with the 0.8/0.2 mix ----
  k_node_pre<float, true><<<ngrid, TPB, 0, stream>>>(M32, nrepr, agg, repr1,
                                                     tvec, uvec, vvec, N_);
  k_quad<float><<<egrid, TPB, 0, stream>>>(S32, rel0, eg0, p32, c32, qv32, E_);
  k_edge_dots<float><<<dgrid, TPB, 0, stream>>>(repr1, rel0, src0, dst0, eg0,
                                                tvec, uvec, vvec, p32, pD32, qv32,
                                                lg0, (void*)mkey0, E_);

  // ---- CSR build (tvec/uvec dead after k_edge_dots<float>) ----
  hipMemsetAsync(cnt, 0, (size_t)N_ * 4, stream);
  k_expsum32h<<<egrid, TPB, 0, stream>>>(lg0, mkey0, src0, dst0, s0, cnt, E_);
  const int nblk = (N_ + SCHUNK - 1) / SCHUNK;
  k_scan1<<<nblk, TPB, 0, stream>>>(cnt, offcsr, bsum, N_);
  k_scan2<<<1, TPB, 0, stream>>>(bsum, offcsr, nblk, N_, E_);
  k_scan3<<<ngrid, TPB, 0, stream>>>(offcsr, bsum, cursor, N_);
  k_scatter0<<<egrid, TPB, 0, stream>>>(lg0, s0, src0, dst0, cursor, pk, E_);
  k_gather_final<<<(N_ + 7) / 8, TPB, 0, stream>>>(pk, offcsr, repr1, Wlin, blin, out_repr, N_);
}

// Round 8
// 639.113 us; speedup vs baseline: 1.0082x; 1.0082x over previous
//
#include <hip/hip_runtime.h>
#include <math.h>

#define DD 32
#define DD4 128
#define TPB 256
#define LDSCAP 6144
#define CANDCAP 2048

// ---------- sortable key mappings ----------
__device__ __forceinline__ unsigned long long dsort_key(double x) {
  unsigned long long b = (unsigned long long)__double_as_longlong(x);
  return (b & 0x8000000000000000ull) ? ~b : (b | 0x8000000000000000ull);
}
__device__ __forceinline__ double dunsort_key(unsigned long long k) {
  unsigned long long b = (k & 0x8000000000000000ull) ? (k ^ 0x8000000000000000ull) : ~k;
  return __longlong_as_double((long long)b);
}
__device__ __forceinline__ unsigned int fsort_key(float x) {
  unsigned int b = __float_as_uint(x);
  return (b & 0x80000000u) ? ~b : (b | 0x80000000u);
}
__device__ __forceinline__ float funsort_key(unsigned int k) {
  unsigned int b = (k & 0x80000000u) ? (k ^ 0x80000000u) : ~k;
  return __uint_as_float(b);
}

// inclusive scan over 256 threads (4 waves of 64). All 256 threads must call.
// Contains 2 barriers; wsum must be a 4-int LDS buffer.
__device__ __forceinline__ int block_iscan256(int x, int* wsum) {
  const int lane = threadIdx.x & 63, w = threadIdx.x >> 6;
#pragma unroll
  for (int o = 1; o < 64; o <<= 1) {
    int y = __shfl_up(x, o, 64);
    if (lane >= o) x += y;
  }
  if (lane == 63) wsum[w] = x;
  __syncthreads();
  int add = 0;
#pragma unroll
  for (int i = 0; i < 4; ++i) add += (i < w) ? wsum[i] : 0;
  __syncthreads();  // allow wsum reuse by a later call
  return x + add;
}

// ---------- K1: M = Wq^T Wk (f64 + f32 mirror) ----------
__global__ __launch_bounds__(TPB) void k_precompute_M(
    const float* __restrict__ Wq, const float* __restrict__ Wk,
    double* __restrict__ M64, float* __restrict__ M32) {
  int t = blockIdx.x * blockDim.x + threadIdx.x;  // 16384 threads
  int i = t >> 7, j = t & 127;
  double acc = 0.0;
  for (int k = 0; k < DD4; ++k)
    acc += (double)Wq[k * DD4 + i] * (double)Wk[k * DD4 + j];
  M64[i * DD4 + j] = acc;
  M32[i * DD4 + j] = (float)acc;
}

// ---------- K1b: symmetrized G22: S[i][j] = G22ij+G22ji (j>i), diag (j==i), 0 (j<i) ----------
__global__ __launch_bounds__(TPB) void k_sym22(
    const double* __restrict__ M64, double* __restrict__ S64, float* __restrict__ S32) {
  int i = blockIdx.x * blockDim.x + threadIdx.x;  // 1024 threads
  int r = i >> 5, c = i & 31;
  double g  = M64[(32 + r) * DD4 + 32 + c];
  double gt = M64[(32 + c) * DD4 + 32 + r];
  double s = (c > r) ? (g + gt) : ((c == r) ? g : 0.0);
  S64[i] = s;
  S32[i] = (float)s;
}

// ---------- K2: per-query precompute p (64), pD (32), c (scalar) ----------
__global__ __launch_bounds__(64) void k_per_query(
    const double* __restrict__ M64,
    const float* __restrict__ qemb, const float* __restrict__ remb,
    double* __restrict__ p64, double* __restrict__ pD64, double* __restrict__ c64,
    float* __restrict__ p32, float* __restrict__ pD32, float* __restrict__ c32) {
  int q = blockIdx.x;
  int l = threadIdx.x;  // 64 threads = 1 wave
  __shared__ double qr[64];
  qr[l] = (l < DD) ? (double)qemb[q * DD + l] : (double)remb[q * DD + (l - DD)];
  __syncthreads();
  double a = 0.0;
  for (int j = 0; j < 64; ++j) a += M64[l * DD4 + 64 + j] * qr[j];
  double ct = 0.0;
  for (int j = 0; j < 64; ++j) ct += M64[(64 + j) * DD4 + l] * qr[j];
  if (l >= DD) a += ct;  // fold rel-part of z^T C x into p (x==y there)
  p64[q * 64 + l] = a;
  p32[q * 64 + l] = (float)a;
  if (l < DD) {
    pD64[q * DD + l] = ct;
    pD32[q * DD + l] = (float)ct;
  }
  double a3 = 0.0;
  for (int j = 0; j < 64; ++j) a3 += M64[(64 + l) * DD4 + 64 + j] * qr[j];
  a3 *= qr[l];
  for (int o = 32; o; o >>= 1) a3 += __shfl_xor(a3, o);
  if (l == 0) { c64[q] = a3; c32[q] = (float)a3; }
}

// ---------- K3: per-node precompute t = G11 h, u = G12^T h, v = G21 h ----------
// Thread-per-node, h in registers (compile-time indices). G is wave-uniform and
// read DIRECTLY from Mmat with uniform indices -> scalar loads into SGPRs
// (v_fma takes one SGPR operand) -> zero LDS/shfl in the compute loop.
// Outputs go through an LDS transpose tile so global stores are coalesced.
// MIX: h = 0.8*agg + 0.2*reprIn, also written (coalesced) to reprOut.
#define G_T(c) Mmat[(c) * DD4 + j]
#define G_U(c) Mmat[j * DD4 + 32 + (c)]
#define G_V(c) Mmat[(32 + (c)) * DD4 + j]

#define NP_TILE(GEXPR)                                                          \
  for (int tt = 0; tt < 4; ++tt) {                                              \
    T a0=(T)0,a1=(T)0,a2=(T)0,a3=(T)0,a4=(T)0,a5=(T)0,a6=(T)0,a7=(T)0;          \
    const int c0 = tt * 8;                                                      \
    _Pragma("unroll")                                                           \
    for (int j = 0; j < 32; ++j) {                                              \
      const T hj = hh[j];                                                       \
      a0 += (GEXPR(c0 + 0)) * hj; a1 += (GEXPR(c0 + 1)) * hj;                   \
      a2 += (GEXPR(c0 + 2)) * hj; a3 += (GEXPR(c0 + 3)) * hj;                   \
      a4 += (GEXPR(c0 + 4)) * hj; a5 += (GEXPR(c0 + 5)) * hj;                   \
      a6 += (GEXPR(c0 + 6)) * hj; a7 += (GEXPR(c0 + 7)) * hj;                   \
    }                                                                           \
    xq[tid * 9 + tt * 2]     = make_float4((float)a0,(float)a1,(float)a2,(float)a3); \
    xq[tid * 9 + tt * 2 + 1] = make_float4((float)a4,(float)a5,(float)a6,(float)a7); \
  }

#define NP_STORE(dst)                                                           \
  __syncthreads();                                                              \
  {                                                                             \
    float4* go = (float4*)(dst) + (size_t)nbase * 8;                            \
    _Pragma("unroll")                                                           \
    for (int k = 0; k < 8; ++k) {                                               \
      int f = k * TPB + tid;                                                    \
      if ((f >> 3) < nlim) go[f] = xq[(f >> 3) * 9 + (f & 7)];                  \
    }                                                                           \
  }                                                                             \
  __syncthreads();

template <typename T, bool MIX>
__global__ __launch_bounds__(TPB) void k_node_pre(
    const T* __restrict__ Mmat, const float* __restrict__ reprIn,
    const float* __restrict__ aggIn, float* __restrict__ reprOut,
    float* __restrict__ t, float* __restrict__ u, float* __restrict__ v, int N_) {
  __shared__ float xp[TPB * 36];   // stride 9 float4s -> bank-balanced
  float4* xq = (float4*)xp;
  const int tid = threadIdx.x;
  const int nbase = blockIdx.x * TPB;
  const int n = nbase + tid;
  const int nlim = min(TPB, N_ - nbase);
  const bool valid = tid < nlim;
  T hh[32];
  if (valid) {
    const float4* h4 = (const float4*)reprIn + (size_t)n * 8;
#pragma unroll
    for (int jq = 0; jq < 8; ++jq) {
      float4 x = h4[jq];
      if constexpr (MIX) {
        const float4 a = ((const float4*)aggIn)[(size_t)n * 8 + jq];
        x = make_float4(0.8f * a.x + 0.2f * x.x, 0.8f * a.y + 0.2f * x.y,
                        0.8f * a.z + 0.2f * x.z, 0.8f * a.w + 0.2f * x.w);
        xq[tid * 9 + jq] = x;   // stage mixed h for coalesced reprOut store
      }
      hh[4 * jq]     = (T)x.x; hh[4 * jq + 1] = (T)x.y;
      hh[4 * jq + 2] = (T)x.z; hh[4 * jq + 3] = (T)x.w;
    }
  } else {
#pragma unroll
    for (int j = 0; j < 32; ++j) hh[j] = (T)0;
  }
  if constexpr (MIX) {
    NP_STORE(reprOut)
  }
  NP_TILE(G_T)
  NP_STORE(t)
  NP_TILE(G_U)
  NP_STORE(u)
  NP_TILE(G_V)
  NP_STORE(v)
}

// ---------- K4a: per-edge rel-quadratic: quad = c_q + rel·p_rel + sum_{i<=j} S_ij x_i x_j ----------
// S is wave-uniform -> read directly (scalar loads), no LDS staging. Fully
// unrolled (compile-time rl[] indices only).
template <typename T>
__global__ __launch_bounds__(TPB) void k_quad(
    const T* __restrict__ Smat,
    const float* __restrict__ rel, const int* __restrict__ eg,
    const T* __restrict__ pq, const T* __restrict__ cq,
    T* __restrict__ quad, int E) {
  const int e = blockIdx.x * TPB + threadIdx.x;
  if (e >= E) return;
  const int q = eg[e];
  T rl[32];
  {
    const float4* r4 = (const float4*)rel + (size_t)e * 8;
#pragma unroll
    for (int j = 0; j < 8; ++j) {
      float4 x = r4[j];
      rl[4 * j] = (T)x.x; rl[4 * j + 1] = (T)x.y;
      rl[4 * j + 2] = (T)x.z; rl[4 * j + 3] = (T)x.w;
    }
  }
  const T* prow = pq + (size_t)q * 64 + 32;
  T lin0 = (T)0, lin1 = (T)0;
#pragma unroll
  for (int i = 0; i < 32; i += 2) {
    lin0 += prow[i] * rl[i];
    lin1 += prow[i + 1] * rl[i + 1];
  }
  T a0 = cq[q] + lin0, a1 = lin1, a2 = (T)0, a3 = (T)0;
#pragma unroll
  for (int i = 0; i < 32; ++i) {
    T r0 = Smat[i * 32 + i] * rl[i];
    T r1 = (T)0;
#pragma unroll
    for (int j = i + 1; j < 32; ++j) {
      if ((j - i) & 1) r1 += Smat[i * 32 + j] * rl[j];
      else             r0 += Smat[i * 32 + j] * rl[j];
    }
    T rr = (r0 + r1) * rl[i];
    if ((i & 3) == 0) a0 += rr;
    else if ((i & 3) == 1) a1 += rr;
    else if ((i & 3) == 2) a2 += rr;
    else a3 += rr;
  }
  quad[e] = (a0 + a1) + (a2 + a3);
}

// ---------- K4b: 8-lanes-per-edge gather dots + reduce + atomicMax ----------
template <typename T>
__global__ __launch_bounds__(TPB) void k_edge_dots(
    const float* __restrict__ repr, const float* __restrict__ rel,
    const int* __restrict__ src, const int* __restrict__ dst, const int* __restrict__ eg,
    const float* __restrict__ tvec, const float* __restrict__ uvec, const float* __restrict__ vvec,
    const T* __restrict__ pq, const T* __restrict__ pDq, const T* __restrict__ quad,
    T* __restrict__ logits, void* __restrict__ mkey, int E) {
  const long long t = (long long)blockIdx.x * TPB + threadIdx.x;
  const int e = (int)(t >> 3), part = (int)(t & 7);
  if (e >= E) return;
  const int s = src[e], d = dst[e], q = eg[e];
  const float4 hs = ((const float4*)repr)[(size_t)s * 8 + part];
  const float4 td = ((const float4*)tvec)[(size_t)d * 8 + part];
  const float4 hd = ((const float4*)repr)[(size_t)d * 8 + part];
  const float4 rl = ((const float4*)rel)[(size_t)e * 8 + part];
  const float4 us = ((const float4*)uvec)[(size_t)s * 8 + part];
  const float4 vd = ((const float4*)vvec)[(size_t)d * 8 + part];
  const T* p  = pq  + (size_t)q * 64 + part * 4;
  const T* pD = pDq + (size_t)q * DD + part * 4;
  T a = (T)hs.x * ((T)td.x + p[0]) + (T)hs.y * ((T)td.y + p[1]) +
        (T)hs.z * ((T)td.z + p[2]) + (T)hs.w * ((T)td.w + p[3]);
  a += (T)hd.x * pD[0] + (T)hd.y * pD[1] + (T)hd.z * pD[2] + (T)hd.w * pD[3];
  a += (T)rl.x * (T)(us.x + vd.x) + (T)rl.y * (T)(us.y + vd.y) +
       (T)rl.z * (T)(us.z + vd.z) + (T)rl.w * (T)(us.w + vd.w);
  a += __shfl_xor(a, 1);
  a += __shfl_xor(a, 2);
  a += __shfl_xor(a, 4);
  if (part == 0) {
    a += quad[e];
    logits[e] = a;
    if constexpr (sizeof(T) == 8) {
      atomicMax((unsigned long long*)mkey + s, dsort_key((double)a));
    } else {
      atomicMax((unsigned int*)mkey + s, fsort_key((float)a));
    }
  }
}

// ---------- K5: ex = exp(l - m[src]); s[src] += ex (in-place) ----------
__global__ __launch_bounds__(TPB) void k_expsum64(
    double* __restrict__ io, const unsigned long long* __restrict__ mkey,
    const int* __restrict__ src, double* __restrict__ ssum, int E) {
  int e = blockIdx.x * blockDim.x + threadIdx.x;
  if (e >= E) return;
  int s = src[e];
  double ex = exp(io[e] - dunsort_key(mkey[s]));
  io[e] = ex;
  atomicAdd(&ssum[s], ex);
}
// layer-0 variant: also builds the dst histogram for the CSR (old k_hist fused)
__global__ __launch_bounds__(TPB) void k_expsum32h(
    float* __restrict__ io, const unsigned int* __restrict__ mkey,
    const int* __restrict__ src, const int* __restrict__ dst,
    float* __restrict__ ssum, int* __restrict__ cnt, int E) {
  int e = blockIdx.x * blockDim.x + threadIdx.x;
  if (e >= E) return;
  int s = src[e];
  float ex = expf(io[e] - funsort_key(mkey[s]));
  io[e] = ex;
  atomicAdd(&ssum[s], ex);
  atomicAdd(&cnt[dst[e]], 1);
}

// ---------- K6: w1 = ex/s; target key; ALSO qoff[] (old k_qoff fused) ----------
__global__ __launch_bounds__(TPB) void k_weights_target(
    const double* __restrict__ ex, const double* __restrict__ ssum,
    const int* __restrict__ src, const float* __restrict__ score,
    const int* __restrict__ eg, int* __restrict__ qoff,
    float* __restrict__ w1f, unsigned int* __restrict__ tkey, int E, int Q) {
  int e = blockIdx.x * blockDim.x + threadIdx.x;
  if (e >= E) return;
  int s = src[e];
  double w = ex[e] / ssum[s];
  float wf = (float)w;
  w1f[e] = wf;
  float tgt = wf * score[s];
  tkey[e] = fsort_key(tgt);
  // qoff[v] = first edge index with eg >= v (eg sorted)
  int cur = eg[e];
  int prev = (e == 0) ? -1 : eg[e - 1];
  for (int v = prev + 1; v <= cur; ++v) qoff[v] = e;
  if (e == E - 1) {
    for (int v = cur + 1; v <= Q; ++v) qoff[v] = E;
  }
}

// ---------- K7: per-query top-k via radix select ----------
// Parallel digit select (shfl suffix-scan) + candidate compaction after pass 0.
__global__ __launch_bounds__(TPB) void k_topk(
    const unsigned int* __restrict__ tkey, const float* __restrict__ w1f,
    const int* __restrict__ qoff, const int* __restrict__ maxe,
    float* __restrict__ w1p, int E) {
  __shared__ unsigned int keys[LDSCAP];
  __shared__ int hist[256];
  __shared__ unsigned short cand[CANDCAP];
  __shared__ int wsum[4];
  __shared__ int sh_cnt;
  __shared__ unsigned int sh_prefix;
  __shared__ int sh_need;
  const int q = blockIdx.x;
  const int s = qoff[q], e2 = qoff[q + 1];
  const int n = e2 - s;
  const int K = maxe[0];
  if (n <= K) {
    for (int i = s + threadIdx.x; i < e2; i += TPB) w1p[i] = w1f[i];
    return;
  }
  const bool useLds = (n <= LDSCAP);
  if (useLds) {
    for (int i = threadIdx.x; i < n; i += TPB) keys[i] = tkey[s + i];
  }
  // ---- pass 0: histogram of top byte ----
  hist[threadIdx.x] = 0;
  __syncthreads();
  for (int i = threadIdx.x; i < n; i += TPB) {
    unsigned int k = useLds ? keys[i] : tkey[s + i];
    atomicAdd(&hist[k >> 24], 1);
  }
  __syncthreads();
  int need = K;
  {
    int h = hist[255 - threadIdx.x];
    int incl = block_iscan256(h, wsum);     // suffix sum (descending digit)
    int excl = incl - h;
    if (incl >= need && excl < need) {
      sh_prefix = (unsigned int)(255 - threadIdx.x) << 24;
      sh_need = need - excl;
    }
  }
  __syncthreads();
  unsigned int prefix = sh_prefix;
  need = sh_need;
  // ---- compact candidates matching the leading digit ----
  const int cnt0 = hist[prefix >> 24];
  const bool compact = useLds && (cnt0 <= CANDCAP);
  if (threadIdx.x == 0) sh_cnt = 0;
  __syncthreads();
  if (compact) {
    const unsigned int d0 = prefix >> 24;
    for (int i = threadIdx.x; i < n; i += TPB) {
      if ((keys[i] >> 24) == d0) {
        int p = atomicAdd(&sh_cnt, 1);
        cand[p] = (unsigned short)i;
      }
    }
  }
  __syncthreads();
  const int ncand = compact ? sh_cnt : 0;
  // ---- passes 1..3 ----
  for (int pass = 1; pass < 4; ++pass) {
    const int shift = 24 - 8 * pass;
    const unsigned int himask = 0xFFFFFFFFu << (shift + 8);
    hist[threadIdx.x] = 0;
    __syncthreads();
    if (compact) {
      for (int ci = threadIdx.x; ci < ncand; ci += TPB) {
        unsigned int k = keys[cand[ci]];
        if ((k & himask) == prefix) atomicAdd(&hist[(k >> shift) & 255], 1);
      }
    } else {
      for (int i = threadIdx.x; i < n; i += TPB) {
        unsigned int k = useLds ? keys[i] : tkey[s + i];
        if ((k & himask) == prefix) atomicAdd(&hist[(k >> shift) & 255], 1);
      }
    }
    __syncthreads();
    int h = hist[255 - threadIdx.x];
    int incl = block_iscan256(h, wsum);
    int excl = incl - h;
    if (incl >= need && excl < need) {
      sh_prefix = prefix | ((unsigned int)(255 - threadIdx.x) << shift);
      sh_need = need - excl;
    }
    __syncthreads();
    prefix = sh_prefix;
    need = sh_need;
    __syncthreads();
  }
  const unsigned int kth = prefix;   // exact kth-largest key
  const int r = need;                // # of kth-valued ties to keep (index order)
  // ---- tie ranks via contiguous chunks + shfl block scan ----
  const int C = (n + TPB - 1) / TPB;
  const int b0 = min(threadIdx.x * C, n);
  const int b1 = min(b0 + C, n);
  int myt = 0;
  for (int i = b0; i < b1; ++i) {
    unsigned int k = useLds ? keys[i] : tkey[s + i];
    myt += (k == kth) ? 1 : 0;
  }
  int tincl = block_iscan256(myt, wsum);
  int tiepre = tincl - myt;  // exclusive prefix of ties before my chunk
  for (int i = b0; i < b1; ++i) {
    unsigned int k = useLds ? keys[i] : tkey[s + i];
    float v = 0.f;
    if (k > kth) {
      v = w1f[s + i];
    } else if (k == kth) {
      if (tiepre < r) v = w1f[s + i];
      ++tiepre;
    }
    w1p[s + i] = v;
  }
}

// ---------- K8: layer-1 scatter: score + repr agg over kept edges (sparse) ----------
__global__ __launch_bounds__(TPB) void k_apply1(
    const float* __restrict__ w1p, const int* __restrict__ src, const int* __restrict__ dst,
    const float* __restrict__ repr0, const float* __restrict__ score,
    float* __restrict__ agg, float* __restrict__ score_out, int E) {
  int t = blockIdx.x * blockDim.x + threadIdx.x;
  int e = t >> 3, part = t & 7;
  if (e >= E) return;
  float w = w1p[e];
  if (w == 0.f) return;
  int sv = src[e], dv = dst[e];
  const float4 rv = ((const float4*)repr0)[sv * 8 + part];
  float* ap = agg + (size_t)dv * DD + part * 4;
  atomicAdd(ap + 0, w * rv.x);
  atomicAdd(ap + 1, w * rv.y);
  atomicAdd(ap + 2, w * rv.z);
  atomicAdd(ap + 3, w * rv.w);
  if (part == 0) atomicAdd(score_out + dv, w * score[sv]);
}

// ---------- CSR scans ----------
#define SCHUNK 1024
__global__ __launch_bounds__(TPB) void k_scan1(
    const int* __restrict__ cnt, int* __restrict__ off, int* __restrict__ bsum, int N_) {
  __shared__ int sd[TPB];
  const int b = blockIdx.x, t = threadIdx.x;
  const int base = b * SCHUNK + t * 4;
  int v[4];
  int s4 = 0;
#pragma unroll
  for (int k = 0; k < 4; ++k) {
    v[k] = (base + k < N_) ? cnt[base + k] : 0;
    s4 += v[k];
  }
  sd[t] = s4;
  __syncthreads();
  for (int o = 1; o < TPB; o <<= 1) {
    int x = (t >= o) ? sd[t - o] : 0;
    __syncthreads();
    sd[t] += x;
    __syncthreads();
  }
  int excl = sd[t] - s4;
  if (t == TPB - 1) bsum[b] = sd[t];
  int run = excl;
#pragma unroll
  for (int k = 0; k < 4; ++k) {
    if (base + k < N_) { off[base + k] = run; run += v[k]; }
  }
}

// parallel exclusive scan over bsum (nblk <= 256 fast path; serial fallback)
__global__ __launch_bounds__(TPB) void k_scan2(
    int* __restrict__ bsum, int* __restrict__ off, int nblk, int N_, int E) {
  __shared__ int wsum[4];
  if (nblk <= TPB) {
    int t = threadIdx.x;
    int x = (t < nblk) ? bsum[t] : 0;
    int orig = x;
    const int lane = t & 63, w = t >> 6;
#pragma unroll
    for (int o = 1; o < 64; o <<= 1) {
      int y = __shfl_up(x, o, 64);
      if (lane >= o) x += y;
    }
    if (lane == 63) wsum[w] = x;
    __syncthreads();
    int add = 0;
#pragma unroll
    for (int i = 0; i < 4; ++i) add += (i < w) ? wsum[i] : 0;
    x += add;
    if (t < nblk) bsum[t] = x - orig;   // exclusive
    if (t == 0) off[N_] = E;
  } else {
    if (threadIdx.x != 0) return;
    int run = 0;
    for (int i = 0; i < nblk; ++i) { int tmp = bsum[i]; bsum[i] = run; run += tmp; }
    off[N_] = E;
  }
}

__global__ __launch_bounds__(TPB) void k_scan3(
    int* __restrict__ off, const int* __restrict__ bsum, int* __restrict__ cursor, int N_) {
  int i = blockIdx.x * blockDim.x + threadIdx.x;
  if (i >= N_) return;
  int v = off[i] + bsum[i >> 10];
  off[i] = v;
  cursor[i] = v;
}

// ---------- K12a: scatter packed {w, src} into dst-CSR order ----------
__global__ __launch_bounds__(TPB) void k_scatter0(
    const float* __restrict__ ex, const float* __restrict__ ssum,
    const int* __restrict__ src, const int* __restrict__ dst,
    int* __restrict__ cursor, float2* __restrict__ pk, int E) {
  int e = blockIdx.x * blockDim.x + threadIdx.x;
  if (e >= E) return;
  int s = src[e];
  float w = ex[e] / ssum[s];
  int pos = atomicAdd(&cursor[dst[e]], 1);
  pk[pos] = make_float2(w, __int_as_float(s));
}

// ---------- K12b: gather per dst node + fused mix + Linear + LeakyReLU ----------
// Manual 4-edge unroll with named scalars: the 4 repr1 gathers are independent
// and issue back-to-back (4x memory-level parallelism vs the rolled loop the
// compiler could not pipeline). Accumulation order (ascending j) unchanged.
__global__ __launch_bounds__(TPB) void k_gather_final(
    const float2* __restrict__ pk, const int* __restrict__ off,
    const float* __restrict__ repr1,
    const float* __restrict__ Wlin, const float* __restrict__ blin,
    float* __restrict__ out_repr, int N_) {
  __shared__ float WsT[DD * DD];   // WsT[j*32+i] = Wlin[i*32+j]
  __shared__ float bs[DD];
  for (int i = threadIdx.x; i < DD * DD; i += TPB) {
    int r = i >> 5, c = i & 31;
    WsT[c * DD + r] = Wlin[i];
  }
  if (threadIdx.x < DD) bs[threadIdx.x] = blin[threadIdx.x];
  __syncthreads();
  const int n = blockIdx.x * 8 + (threadIdx.x >> 5);  // node
  const int c = threadIdx.x & 31;                     // component
  if (n >= N_) return;
  const float self = repr1[(size_t)n * DD + c];       // hoisted off the chain
  float acc = 0.f;
  const int j0 = off[n], j1 = off[n + 1];
  for (int base = j0; base < j1; base += 32) {
    const int m = min(32, j1 - base);
    float2 p = (base + c < j1) ? pk[base + c] : make_float2(0.f, 0.f);
    const int pw = __float_as_int(p.x);
    const int ps = __float_as_int(p.y);
    int j = 0;
    for (; j + 4 <= m; j += 4) {
      const float w0 = __int_as_float(__shfl(pw, j, 32));
      const float w1 = __int_as_float(__shfl(pw, j + 1, 32));
      const float w2 = __int_as_float(__shfl(pw, j + 2, 32));
      const float w3 = __int_as_float(__shfl(pw, j + 3, 32));
      const int s0 = __shfl(ps, j, 32);
      const int s1 = __shfl(ps, j + 1, 32);
      const int s2 = __shfl(ps, j + 2, 32);
      const int s3 = __shfl(ps, j + 3, 32);
      const float g0 = repr1[(size_t)s0 * DD + c];
      const float g1 = repr1[(size_t)s1 * DD + c];
      const float g2 = repr1[(size_t)s2 * DD + c];
      const float g3 = repr1[(size_t)s3 * DD + c];
      acc += w0 * g0;
      acc += w1 * g1;
      acc += w2 * g2;
      acc += w3 * g3;
    }
    for (; j < m; ++j) {
      const float wj = __int_as_float(__shfl(pw, j, 32));
      const int sj = __shfl(ps, j, 32);
      acc += wj * repr1[(size_t)sj * DD + c];
    }
  }
  float mix = 0.8f * acc + 0.2f * self;
  float o = bs[c];
#pragma unroll 8
  for (int j = 0; j < DD; ++j) {
    float mj = __shfl(mix, j, 32);
    o += WsT[j * DD + c] * mj;
  }
  out_repr[(size_t)n * DD + c] = (o >= 0.f) ? o : 0.01f * o;
}

extern "C" void kernel_launch(void* const* d_in, const int* in_sizes, int n_in,
                              void* d_out, int out_size, void* d_ws, size_t ws_size,
                              hipStream_t stream) {
  (void)n_in; (void)out_size; (void)ws_size;
  const float* score = (const float*)d_in[0];
  const float* nrepr = (const float*)d_in[1];
  const int*   eg0   = (const int*)d_in[2];
  const int*   src0  = (const int*)d_in[3];
  const int*   dst0  = (const int*)d_in[4];
  const float* rel0  = (const float*)d_in[5];
  const int*   eg1   = (const int*)d_in[6];
  const int*   src1  = (const int*)d_in[7];
  const int*   dst1  = (const int*)d_in[8];
  const float* rel1  = (const float*)d_in[9];
  const float* qemb  = (const float*)d_in[10];
  const float* remb  = (const float*)d_in[11];
  const float* Wq    = (const float*)d_in[12];
  const float* Wk    = (const float*)d_in[13];
  const float* Wlin  = (const float*)d_in[14];
  const float* blin  = (const float*)d_in[15];
  const int*   maxe  = (const int*)d_in[16];

  const int N_ = in_sizes[0];
  const int E_ = in_sizes[2];
  const int Q_ = in_sizes[10] / DD;

  char* wsc = (char*)d_ws;
  size_t off = 0;
  auto alloc = [&](size_t bytes) -> void* {
    void* p = wsc + off;
    off += (bytes + 255) & ~(size_t)255;
    return p;
  };
  double* M64  = (double*)alloc((size_t)DD4 * DD4 * 8);
  float*  M32  = (float*)alloc((size_t)DD4 * DD4 * 4);
  double* S64  = (double*)alloc((size_t)DD * DD * 8);
  float*  S32  = (float*)alloc((size_t)DD * DD * 4);
  double* p64  = (double*)alloc((size_t)Q_ * 64 * 8);
  double* pD64 = (double*)alloc((size_t)Q_ * DD * 8);
  double* c64  = (double*)alloc((size_t)Q_ * 8);
  float*  p32  = (float*)alloc((size_t)Q_ * 64 * 4);
  float*  pD32 = (float*)alloc((size_t)Q_ * DD * 4);
  float*  c32  = (float*)alloc((size_t)Q_ * 4);
  int*    qoff = (int*)alloc((size_t)(Q_ + 2) * 4);
  double* lg1  = (double*)alloc((size_t)E_ * 8);
  double* qv64 = (double*)alloc((size_t)E_ * 8);   // per-edge rel-quadratic (reused as f32 for layer 0)
  float*  w1f  = (float*)alloc((size_t)E_ * 4);
  unsigned int* tkey = (unsigned int*)alloc((size_t)E_ * 4);
  float*  w1p  = (float*)alloc((size_t)E_ * 4);
  float*  lg0  = (float*)alloc((size_t)E_ * 4);
  float*  repr1 = (float*)alloc((size_t)N_ * DD * 4);
  float*  tvec = (float*)alloc((size_t)N_ * DD * 4);   // reused: node-pre, then CSR scratch
  float*  uvec = (float*)alloc((size_t)N_ * DD * 4);   // reused: then pk
  float*  vvec = (float*)alloc((size_t)N_ * DD * 4);
  // zero-initialized region (contiguous)
  size_t zstart = off;
  unsigned long long* mkey1 = (unsigned long long*)alloc((size_t)N_ * 8);
  double* s1   = (double*)alloc((size_t)N_ * 8);
  float*  agg  = (float*)alloc((size_t)N_ * DD * 4);
  unsigned int* mkey0 = (unsigned int*)alloc((size_t)N_ * 4);
  float*  s0   = (float*)alloc((size_t)N_ * 4);
  size_t zlen = off - zstart;

  float* qv32 = (float*)qv64;   // layer-0 reuse (layer-1 consumer already done)

  // CSR scratch aliases tvec/uvec (dead after k_edge_dots<float>).
  // NOTE padding: offcsr needs N+1 ints — cursor must start past offcsr[N].
  int* cnt    = (int*)tvec;                         // [0, N)
  int* offcsr = (int*)tvec + N_;                    // [N, 2N+1)  (N+1 ints!)
  int* cursor = (int*)tvec + 2 * (size_t)N_ + 64;   // padded past offcsr[N]
  int* bsum   = (int*)tvec + 3 * (size_t)N_ + 128;  // nblk ints
  float2* pk  = (float2*)uvec;                      // E float2 = 4 MB (uvec is 12.8 MB)

  float* out_score = (float*)d_out;
  float* out_repr  = out_score + N_;

  hipMemsetAsync(wsc + zstart, 0, zlen, stream);
  hipMemsetAsync(d_out, 0, (size_t)N_ * 4, stream);

  k_precompute_M<<<(DD4 * DD4) / TPB, TPB, 0, stream>>>(Wq, Wk, M64, M32);
  k_sym22<<<4, TPB, 0, stream>>>(M64, S64, S32);
  k_per_query<<<Q_, 64, 0, stream>>>(M64, qemb, remb, p64, pD64, c64, p32, pD32, c32);

  const int ngrid = (N_ + TPB - 1) / TPB;
  const int egrid = (E_ + TPB - 1) / TPB;
  const int dgrid = (int)(((size_t)E_ * 8 + TPB - 1) / TPB);

  // ---- layer 1 (f64 logits path, selection-critical) ----
  k_node_pre<double, false><<<ngrid, TPB, 0, stream>>>(M64, nrepr, nullptr, nullptr,
                                                       tvec, uvec, vvec, N_);
  k_quad<double><<<egrid, TPB, 0, stream>>>(S64, rel1, eg1, p64, c64, qv64, E_);
  k_edge_dots<double><<<dgrid, TPB, 0, stream>>>(nrepr, rel1, src1, dst1, eg1,
                                                 tvec, uvec, vvec, p64, pD64, qv64,
                                                 lg1, (void*)mkey1, E_);
  k_expsum64<<<egrid, TPB, 0, stream>>>(lg1, mkey1, src1, s1, E_);
  k_weights_target<<<egrid, TPB, 0, stream>>>(lg1, s1, src1, score, eg1, qoff,
                                              w1f, tkey, E_, Q_);
  k_topk<<<Q_, TPB, 0, stream>>>(tkey, w1f, qoff, maxe, w1p, E_);

  k_apply1<<<dgrid, TPB, 0, stream>>>(w1p, src1, dst1, nrepr, score, agg, out_score, E_);

  // ---- layer 0 (f32): node-pre fused with the 0.8/0.2 mix ----
  k_node_pre<float, true><<<ngrid, TPB, 0, stream>>>(M32, nrepr, agg, repr1,
                                                     tvec, uvec, vvec, N_);
  k_quad<float><<<egrid, TPB, 0, stream>>>(S32, rel0, eg0, p32, c32, qv32, E_);
  k_edge_dots<float><<<dgrid, TPB, 0, stream>>>(repr1, rel0, src0, dst0, eg0,
                                                tvec, uvec, vvec, p32, pD32, qv32,
                                                lg0, (void*)mkey0, E_);

  // ---- CSR build (tvec/uvec dead after k_edge_dots<float>) ----
  hipMemsetAsync(cnt, 0, (size_t)N_ * 4, stream);
  k_expsum32h<<<egrid, TPB, 0, stream>>>(lg0, mkey0, src0, dst0, s0, cnt, E_);
  const int nblk = (N_ + SCHUNK - 1) / SCHUNK;
  k_scan1<<<nblk, TPB, 0, stream>>>(cnt, offcsr, bsum, N_);
  k_scan2<<<1, TPB, 0, stream>>>(bsum, offcsr, nblk, N_, E_);
  k_scan3<<<ngrid, TPB, 0, stream>>>(offcsr, bsum, cursor, N_);
  k_scatter0<<<egrid, TPB, 0, stream>>>(lg0, s0, src0, dst0, cursor, pk, E_);
  k_gather_final<<<(N_ + 7) / 8, TPB, 0, stream>>>(pk, offcsr, repr1, Wlin, blin, out_repr, N_);
}

// Round 9
// 623.360 us; speedup vs baseline: 1.0337x; 1.0253x over previous
//
#include <hip/hip_runtime.h>
#include <math.h>

#define DD 32
#define DD4 128
#define TPB 256
#define LDSCAP 6144
#define CANDCAP 2048

// ---------- sortable key mappings ----------
__device__ __forceinline__ unsigned long long dsort_key(double x) {
  unsigned long long b = (unsigned long long)__double_as_longlong(x);
  return (b & 0x8000000000000000ull) ? ~b : (b | 0x8000000000000000ull);
}
__device__ __forceinline__ double dunsort_key(unsigned long long k) {
  unsigned long long b = (k & 0x8000000000000000ull) ? (k ^ 0x8000000000000000ull) : ~k;
  return __longlong_as_double((long long)b);
}
__device__ __forceinline__ unsigned int fsort_key(float x) {
  unsigned int b = __float_as_uint(x);
  return (b & 0x80000000u) ? ~b : (b | 0x80000000u);
}
__device__ __forceinline__ float funsort_key(unsigned int k) {
  unsigned int b = (k & 0x80000000u) ? (k ^ 0x80000000u) : ~k;
  return __uint_as_float(b);
}

// inclusive scan over 256 threads (4 waves of 64). All 256 threads must call.
// Contains 2 barriers; wsum must be a 4-int LDS buffer.
__device__ __forceinline__ int block_iscan256(int x, int* wsum) {
  const int lane = threadIdx.x & 63, w = threadIdx.x >> 6;
#pragma unroll
  for (int o = 1; o < 64; o <<= 1) {
    int y = __shfl_up(x, o, 64);
    if (lane >= o) x += y;
  }
  if (lane == 63) wsum[w] = x;
  __syncthreads();
  int add = 0;
#pragma unroll
  for (int i = 0; i < 4; ++i) add += (i < w) ? wsum[i] : 0;
  __syncthreads();  // allow wsum reuse by a later call
  return x + add;
}

// ---------- K1: M = Wq^T Wk (f64 + f32 mirror) ----------
__global__ __launch_bounds__(TPB) void k_precompute_M(
    const float* __restrict__ Wq, const float* __restrict__ Wk,
    double* __restrict__ M64, float* __restrict__ M32) {
  int t = blockIdx.x * blockDim.x + threadIdx.x;  // 16384 threads
  int i = t >> 7, j = t & 127;
  double acc = 0.0;
  for (int k = 0; k < DD4; ++k)
    acc += (double)Wq[k * DD4 + i] * (double)Wk[k * DD4 + j];
  M64[i * DD4 + j] = acc;
  M32[i * DD4 + j] = (float)acc;
}

// ---------- K1b: symmetrized G22: S[i][j] = G22ij+G22ji (j>i), diag (j==i), 0 (j<i) ----------
__global__ __launch_bounds__(TPB) void k_sym22(
    const double* __restrict__ M64, double* __restrict__ S64, float* __restrict__ S32) {
  int i = blockIdx.x * blockDim.x + threadIdx.x;  // 1024 threads
  int r = i >> 5, c = i & 31;
  double g  = M64[(32 + r) * DD4 + 32 + c];
  double gt = M64[(32 + c) * DD4 + 32 + r];
  double s = (c > r) ? (g + gt) : ((c == r) ? g : 0.0);
  S64[i] = s;
  S32[i] = (float)s;
}

// ---------- K2: per-query precompute p (64), pD (32), c (scalar) ----------
__global__ __launch_bounds__(64) void k_per_query(
    const double* __restrict__ M64,
    const float* __restrict__ qemb, const float* __restrict__ remb,
    double* __restrict__ p64, double* __restrict__ pD64, double* __restrict__ c64,
    float* __restrict__ p32, float* __restrict__ pD32, float* __restrict__ c32) {
  int q = blockIdx.x;
  int l = threadIdx.x;  // 64 threads = 1 wave
  __shared__ double qr[64];
  qr[l] = (l < DD) ? (double)qemb[q * DD + l] : (double)remb[q * DD + (l - DD)];
  __syncthreads();
  double a = 0.0;
  for (int j = 0; j < 64; ++j) a += M64[l * DD4 + 64 + j] * qr[j];
  double ct = 0.0;
  for (int j = 0; j < 64; ++j) ct += M64[(64 + j) * DD4 + l] * qr[j];
  if (l >= DD) a += ct;  // fold rel-part of z^T C x into p (x==y there)
  p64[q * 64 + l] = a;
  p32[q * 64 + l] = (float)a;
  if (l < DD) {
    pD64[q * DD + l] = ct;
    pD32[q * DD + l] = (float)ct;
  }
  double a3 = 0.0;
  for (int j = 0; j < 64; ++j) a3 += M64[(64 + l) * DD4 + 64 + j] * qr[j];
  a3 *= qr[l];
  for (int o = 32; o; o >>= 1) a3 += __shfl_xor(a3, o);
  if (l == 0) { c64[q] = a3; c32[q] = (float)a3; }
}

// ---------- K3: per-node precompute t = G11 h, u = G12^T h, v = G21 h ----------
// Thread-per-node, h in registers (compile-time indices). G is wave-uniform and
// read DIRECTLY from Mmat with uniform indices -> scalar loads into SGPRs.
// Outputs go through an LDS transpose tile so global stores are coalesced.
// MIX: h = 0.8*agg + 0.2*reprIn, also written (coalesced) to reprOut.
#define G_T(c) Mmat[(c) * DD4 + j]
#define G_U(c) Mmat[j * DD4 + 32 + (c)]
#define G_V(c) Mmat[(32 + (c)) * DD4 + j]

#define NP_TILE(GEXPR)                                                          \
  for (int tt = 0; tt < 4; ++tt) {                                              \
    T a0=(T)0,a1=(T)0,a2=(T)0,a3=(T)0,a4=(T)0,a5=(T)0,a6=(T)0,a7=(T)0;          \
    const int c0 = tt * 8;                                                      \
    _Pragma("unroll")                                                           \
    for (int j = 0; j < 32; ++j) {                                              \
      const T hj = hh[j];                                                       \
      a0 += (GEXPR(c0 + 0)) * hj; a1 += (GEXPR(c0 + 1)) * hj;                   \
      a2 += (GEXPR(c0 + 2)) * hj; a3 += (GEXPR(c0 + 3)) * hj;                   \
      a4 += (GEXPR(c0 + 4)) * hj; a5 += (GEXPR(c0 + 5)) * hj;                   \
      a6 += (GEXPR(c0 + 6)) * hj; a7 += (GEXPR(c0 + 7)) * hj;                   \
    }                                                                           \
    xq[tid * 9 + tt * 2]     = make_float4((float)a0,(float)a1,(float)a2,(float)a3); \
    xq[tid * 9 + tt * 2 + 1] = make_float4((float)a4,(float)a5,(float)a6,(float)a7); \
  }

#define NP_STORE(dst)                                                           \
  __syncthreads();                                                              \
  {                                                                             \
    float4* go = (float4*)(dst) + (size_t)nbase * 8;                            \
    _Pragma("unroll")                                                           \
    for (int k = 0; k < 8; ++k) {                                               \
      int f = k * TPB + tid;                                                    \
      if ((f >> 3) < nlim) go[f] = xq[(f >> 3) * 9 + (f & 7)];                  \
    }                                                                           \
  }                                                                             \
  __syncthreads();

template <typename T, bool MIX>
__global__ __launch_bounds__(TPB) void k_node_pre(
    const T* __restrict__ Mmat, const float* __restrict__ reprIn,
    const float* __restrict__ aggIn, float* __restrict__ reprOut,
    float* __restrict__ t, float* __restrict__ u, float* __restrict__ v, int N_) {
  __shared__ float xp[TPB * 36];   // stride 9 float4s -> bank-balanced
  float4* xq = (float4*)xp;
  const int tid = threadIdx.x;
  const int nbase = blockIdx.x * TPB;
  const int n = nbase + tid;
  const int nlim = min(TPB, N_ - nbase);
  const bool valid = tid < nlim;
  T hh[32];
  if (valid) {
    const float4* h4 = (const float4*)reprIn + (size_t)n * 8;
#pragma unroll
    for (int jq = 0; jq < 8; ++jq) {
      float4 x = h4[jq];
      if constexpr (MIX) {
        const float4 a = ((const float4*)aggIn)[(size_t)n * 8 + jq];
        x = make_float4(0.8f * a.x + 0.2f * x.x, 0.8f * a.y + 0.2f * x.y,
                        0.8f * a.z + 0.2f * x.z, 0.8f * a.w + 0.2f * x.w);
        xq[tid * 9 + jq] = x;   // stage mixed h for coalesced reprOut store
      }
      hh[4 * jq]     = (T)x.x; hh[4 * jq + 1] = (T)x.y;
      hh[4 * jq + 2] = (T)x.z; hh[4 * jq + 3] = (T)x.w;
    }
  } else {
#pragma unroll
    for (int j = 0; j < 32; ++j) hh[j] = (T)0;
  }
  if constexpr (MIX) {
    NP_STORE(reprOut)
  }
  NP_TILE(G_T)
  NP_STORE(t)
  NP_TILE(G_U)
  NP_STORE(u)
  NP_TILE(G_V)
  NP_STORE(v)
}

// ---------- K4a: per-edge rel-quadratic: quad = c_q + rel·p_rel + sum_{i<=j} S_ij x_i x_j ----------
// S is wave-uniform -> read directly (scalar loads), no LDS staging. Fully
// unrolled (compile-time rl[] indices only).
template <typename T>
__global__ __launch_bounds__(TPB) void k_quad(
    const T* __restrict__ Smat,
    const float* __restrict__ rel, const int* __restrict__ eg,
    const T* __restrict__ pq, const T* __restrict__ cq,
    T* __restrict__ quad, int E) {
  const int e = blockIdx.x * TPB + threadIdx.x;
  if (e >= E) return;
  const int q = eg[e];
  T rl[32];
  {
    const float4* r4 = (const float4*)rel + (size_t)e * 8;
#pragma unroll
    for (int j = 0; j < 8; ++j) {
      float4 x = r4[j];
      rl[4 * j] = (T)x.x; rl[4 * j + 1] = (T)x.y;
      rl[4 * j + 2] = (T)x.z; rl[4 * j + 3] = (T)x.w;
    }
  }
  const T* prow = pq + (size_t)q * 64 + 32;
  T lin0 = (T)0, lin1 = (T)0;
#pragma unroll
  for (int i = 0; i < 32; i += 2) {
    lin0 += prow[i] * rl[i];
    lin1 += prow[i + 1] * rl[i + 1];
  }
  T a0 = cq[q] + lin0, a1 = lin1, a2 = (T)0, a3 = (T)0;
#pragma unroll
  for (int i = 0; i < 32; ++i) {
    T r0 = Smat[i * 32 + i] * rl[i];
    T r1 = (T)0;
#pragma unroll
    for (int j = i + 1; j < 32; ++j) {
      if ((j - i) & 1) r1 += Smat[i * 32 + j] * rl[j];
      else             r0 += Smat[i * 32 + j] * rl[j];
    }
    T rr = (r0 + r1) * rl[i];
    if ((i & 3) == 0) a0 += rr;
    else if ((i & 3) == 1) a1 += rr;
    else if ((i & 3) == 2) a2 += rr;
    else a3 += rr;
  }
  quad[e] = (a0 + a1) + (a2 + a3);
}

// ---------- K4b: 8-lanes-per-edge gather dots, 2 edges per thread ----------
// 12 independent float4 gathers in flight per thread (vs 6): doubles
// memory-level parallelism against ~600-cycle L3-hit gather latency.
template <typename T>
__global__ __launch_bounds__(TPB) void k_edge_dots(
    const float* __restrict__ repr, const float* __restrict__ rel,
    const int* __restrict__ src, const int* __restrict__ dst, const int* __restrict__ eg,
    const float* __restrict__ tvec, const float* __restrict__ uvec, const float* __restrict__ vvec,
    const T* __restrict__ pq, const T* __restrict__ pDq, const T* __restrict__ quad,
    T* __restrict__ logits, void* __restrict__ mkey, int E) {
  const long long t = (long long)blockIdx.x * TPB + threadIdx.x;
  const int part = (int)(t & 7);
  const int e0 = (int)((t >> 3) * 2);
  if (e0 >= E) return;
  const int e1 = e0 + 1;
  const bool has1 = (e1 < E);
  const int s0 = src[e0], d0 = dst[e0], q0 = eg[e0];
  const int s1 = has1 ? src[e1] : s0;
  const int d1 = has1 ? dst[e1] : d0;
  const int q1 = has1 ? eg[e1] : q0;
  const float4* R  = (const float4*)repr;
  const float4* Tv = (const float4*)tvec;
  const float4* Uv = (const float4*)uvec;
  const float4* Vv = (const float4*)vvec;
  const float4* RL = (const float4*)rel;
  const float4 hs0 = R[(size_t)s0 * 8 + part],  hs1 = R[(size_t)s1 * 8 + part];
  const float4 td0 = Tv[(size_t)d0 * 8 + part], td1 = Tv[(size_t)d1 * 8 + part];
  const float4 hd0 = R[(size_t)d0 * 8 + part],  hd1 = R[(size_t)d1 * 8 + part];
  const float4 us0 = Uv[(size_t)s0 * 8 + part], us1 = Uv[(size_t)s1 * 8 + part];
  const float4 vd0 = Vv[(size_t)d0 * 8 + part], vd1 = Vv[(size_t)d1 * 8 + part];
  const float4 rl0 = RL[(size_t)e0 * 8 + part];
  const float4 rl1 = has1 ? RL[(size_t)e1 * 8 + part] : rl0;
  const T* p0  = pq  + (size_t)q0 * 64 + part * 4;
  const T* p1  = pq  + (size_t)q1 * 64 + part * 4;
  const T* pD0 = pDq + (size_t)q0 * DD + part * 4;
  const T* pD1 = pDq + (size_t)q1 * DD + part * 4;
  T a = (T)hs0.x * ((T)td0.x + p0[0]) + (T)hs0.y * ((T)td0.y + p0[1]) +
        (T)hs0.z * ((T)td0.z + p0[2]) + (T)hs0.w * ((T)td0.w + p0[3]);
  a += (T)hd0.x * pD0[0] + (T)hd0.y * pD0[1] + (T)hd0.z * pD0[2] + (T)hd0.w * pD0[3];
  a += (T)rl0.x * (T)(us0.x + vd0.x) + (T)rl0.y * (T)(us0.y + vd0.y) +
       (T)rl0.z * (T)(us0.z + vd0.z) + (T)rl0.w * (T)(us0.w + vd0.w);
  T b = (T)hs1.x * ((T)td1.x + p1[0]) + (T)hs1.y * ((T)td1.y + p1[1]) +
        (T)hs1.z * ((T)td1.z + p1[2]) + (T)hs1.w * ((T)td1.w + p1[3]);
  b += (T)hd1.x * pD1[0] + (T)hd1.y * pD1[1] + (T)hd1.z * pD1[2] + (T)hd1.w * pD1[3];
  b += (T)rl1.x * (T)(us1.x + vd1.x) + (T)rl1.y * (T)(us1.y + vd1.y) +
       (T)rl1.z * (T)(us1.z + vd1.z) + (T)rl1.w * (T)(us1.w + vd1.w);
  a += __shfl_xor(a, 1); a += __shfl_xor(a, 2); a += __shfl_xor(a, 4);
  b += __shfl_xor(b, 1); b += __shfl_xor(b, 2); b += __shfl_xor(b, 4);
  if (part == 0) {
    a += quad[e0];
    logits[e0] = a;
    if constexpr (sizeof(T) == 8) {
      atomicMax((unsigned long long*)mkey + s0, dsort_key((double)a));
    } else {
      atomicMax((unsigned int*)mkey + s0, fsort_key((float)a));
    }
    if (has1) {
      b += quad[e1];
      logits[e1] = b;
      if constexpr (sizeof(T) == 8) {
        atomicMax((unsigned long long*)mkey + s1, dsort_key((double)b));
      } else {
        atomicMax((unsigned int*)mkey + s1, fsort_key((float)b));
      }
    }
  }
}

// ---------- K5: ex = exp(l - m[src]); s[src] += ex (in-place) ----------
__global__ __launch_bounds__(TPB) void k_expsum64(
    double* __restrict__ io, const unsigned long long* __restrict__ mkey,
    const int* __restrict__ src, double* __restrict__ ssum, int E) {
  int e = blockIdx.x * blockDim.x + threadIdx.x;
  if (e >= E) return;
  int s = src[e];
  double ex = exp(io[e] - dunsort_key(mkey[s]));
  io[e] = ex;
  atomicAdd(&ssum[s], ex);
}
// layer-0 variant: also builds the dst histogram for the CSR (old k_hist fused)
__global__ __launch_bounds__(TPB) void k_expsum32h(
    float* __restrict__ io, const unsigned int* __restrict__ mkey,
    const int* __restrict__ src, const int* __restrict__ dst,
    float* __restrict__ ssum, int* __restrict__ cnt, int E) {
  int e = blockIdx.x * blockDim.x + threadIdx.x;
  if (e >= E) return;
  int s = src[e];
  float ex = expf(io[e] - funsort_key(mkey[s]));
  io[e] = ex;
  atomicAdd(&ssum[s], ex);
  atomicAdd(&cnt[dst[e]], 1);
}

// ---------- K6: w1 = ex/s; target key; ALSO qoff[] (old k_qoff fused) ----------
__global__ __launch_bounds__(TPB) void k_weights_target(
    const double* __restrict__ ex, const double* __restrict__ ssum,
    const int* __restrict__ src, const float* __restrict__ score,
    const int* __restrict__ eg, int* __restrict__ qoff,
    float* __restrict__ w1f, unsigned int* __restrict__ tkey, int E, int Q) {
  int e = blockIdx.x * blockDim.x + threadIdx.x;
  if (e >= E) return;
  int s = src[e];
  double w = ex[e] / ssum[s];
  float wf = (float)w;
  w1f[e] = wf;
  float tgt = wf * score[s];
  tkey[e] = fsort_key(tgt);
  // qoff[v] = first edge index with eg >= v (eg sorted)
  int cur = eg[e];
  int prev = (e == 0) ? -1 : eg[e - 1];
  for (int v = prev + 1; v <= cur; ++v) qoff[v] = e;
  if (e == E - 1) {
    for (int v = cur + 1; v <= Q; ++v) qoff[v] = E;
  }
}

// ---------- K7: per-query top-k via radix select ----------
// Parallel digit select (shfl suffix-scan) + candidate compaction after pass 0.
__global__ __launch_bounds__(TPB) void k_topk(
    const unsigned int* __restrict__ tkey, const float* __restrict__ w1f,
    const int* __restrict__ qoff, const int* __restrict__ maxe,
    float* __restrict__ w1p, int E) {
  __shared__ unsigned int keys[LDSCAP];
  __shared__ int hist[256];
  __shared__ unsigned short cand[CANDCAP];
  __shared__ int wsum[4];
  __shared__ int sh_cnt;
  __shared__ unsigned int sh_prefix;
  __shared__ int sh_need;
  const int q = blockIdx.x;
  const int s = qoff[q], e2 = qoff[q + 1];
  const int n = e2 - s;
  const int K = maxe[0];
  if (n <= K) {
    for (int i = s + threadIdx.x; i < e2; i += TPB) w1p[i] = w1f[i];
    return;
  }
  const bool useLds = (n <= LDSCAP);
  if (useLds) {
    for (int i = threadIdx.x; i < n; i += TPB) keys[i] = tkey[s + i];
  }
  // ---- pass 0: histogram of top byte ----
  hist[threadIdx.x] = 0;
  __syncthreads();
  for (int i = threadIdx.x; i < n; i += TPB) {
    unsigned int k = useLds ? keys[i] : tkey[s + i];
    atomicAdd(&hist[k >> 24], 1);
  }
  __syncthreads();
  int need = K;
  {
    int h = hist[255 - threadIdx.x];
    int incl = block_iscan256(h, wsum);     // suffix sum (descending digit)
    int excl = incl - h;
    if (incl >= need && excl < need) {
      sh_prefix = (unsigned int)(255 - threadIdx.x) << 24;
      sh_need = need - excl;
    }
  }
  __syncthreads();
  unsigned int prefix = sh_prefix;
  need = sh_need;
  // ---- compact candidates matching the leading digit ----
  const int cnt0 = hist[prefix >> 24];
  const bool compact = useLds && (cnt0 <= CANDCAP);
  if (threadIdx.x == 0) sh_cnt = 0;
  __syncthreads();
  if (compact) {
    const unsigned int d0 = prefix >> 24;
    for (int i = threadIdx.x; i < n; i += TPB) {
      if ((keys[i] >> 24) == d0) {
        int p = atomicAdd(&sh_cnt, 1);
        cand[p] = (unsigned short)i;
      }
    }
  }
  __syncthreads();
  const int ncand = compact ? sh_cnt : 0;
  // ---- passes 1..3 ----
  for (int pass = 1; pass < 4; ++pass) {
    const int shift = 24 - 8 * pass;
    const unsigned int himask = 0xFFFFFFFFu << (shift + 8);
    hist[threadIdx.x] = 0;
    __syncthreads();
    if (compact) {
      for (int ci = threadIdx.x; ci < ncand; ci += TPB) {
        unsigned int k = keys[cand[ci]];
        if ((k & himask) == prefix) atomicAdd(&hist[(k >> shift) & 255], 1);
      }
    } else {
      for (int i = threadIdx.x; i < n; i += TPB) {
        unsigned int k = useLds ? keys[i] : tkey[s + i];
        if ((k & himask) == prefix) atomicAdd(&hist[(k >> shift) & 255], 1);
      }
    }
    __syncthreads();
    int h = hist[255 - threadIdx.x];
    int incl = block_iscan256(h, wsum);
    int excl = incl - h;
    if (incl >= need && excl < need) {
      sh_prefix = prefix | ((unsigned int)(255 - threadIdx.x) << shift);
      sh_need = need - excl;
    }
    __syncthreads();
    prefix = sh_prefix;
    need = sh_need;
    __syncthreads();
  }
  const unsigned int kth = prefix;   // exact kth-largest key
  const int r = need;                // # of kth-valued ties to keep (index order)
  // ---- tie ranks via contiguous chunks + shfl block scan ----
  const int C = (n + TPB - 1) / TPB;
  const int b0 = min(threadIdx.x * C, n);
  const int b1 = min(b0 + C, n);
  int myt = 0;
  for (int i = b0; i < b1; ++i) {
    unsigned int k = useLds ? keys[i] : tkey[s + i];
    myt += (k == kth) ? 1 : 0;
  }
  int tincl = block_iscan256(myt, wsum);
  int tiepre = tincl - myt;  // exclusive prefix of ties before my chunk
  for (int i = b0; i < b1; ++i) {
    unsigned int k = useLds ? keys[i] : tkey[s + i];
    float v = 0.f;
    if (k > kth) {
      v = w1f[s + i];
    } else if (k == kth) {
      if (tiepre < r) v = w1f[s + i];
      ++tiepre;
    }
    w1p[s + i] = v;
  }
}

// ---------- K8: layer-1 scatter: score + repr agg over kept edges (sparse) ----------
__global__ __launch_bounds__(TPB) void k_apply1(
    const float* __restrict__ w1p, const int* __restrict__ src, const int* __restrict__ dst,
    const float* __restrict__ repr0, const float* __restrict__ score,
    float* __restrict__ agg, float* __restrict__ score_out, int E) {
  int t = blockIdx.x * blockDim.x + threadIdx.x;
  int e = t >> 3, part = t & 7;
  if (e >= E) return;
  float w = w1p[e];
  if (w == 0.f) return;
  int sv = src[e], dv = dst[e];
  const float4 rv = ((const float4*)repr0)[sv * 8 + part];
  float* ap = agg + (size_t)dv * DD + part * 4;
  atomicAdd(ap + 0, w * rv.x);
  atomicAdd(ap + 1, w * rv.y);
  atomicAdd(ap + 2, w * rv.z);
  atomicAdd(ap + 3, w * rv.w);
  if (part == 0) atomicAdd(score_out + dv, w * score[sv]);
}

// ---------- CSR scans ----------
#define SCHUNK 1024
__global__ __launch_bounds__(TPB) void k_scan1(
    const int* __restrict__ cnt, int* __restrict__ off, int* __restrict__ bsum, int N_) {
  __shared__ int sd[TPB];
  const int b = blockIdx.x, t = threadIdx.x;
  const int base = b * SCHUNK + t * 4;
  int v[4];
  int s4 = 0;
#pragma unroll
  for (int k = 0; k < 4; ++k) {
    v[k] = (base + k < N_) ? cnt[base + k] : 0;
    s4 += v[k];
  }
  sd[t] = s4;
  __syncthreads();
  for (int o = 1; o < TPB; o <<= 1) {
    int x = (t >= o) ? sd[t - o] : 0;
    __syncthreads();
    sd[t] += x;
    __syncthreads();
  }
  int excl = sd[t] - s4;
  if (t == TPB - 1) bsum[b] = sd[t];
  int run = excl;
#pragma unroll
  for (int k = 0; k < 4; ++k) {
    if (base + k < N_) { off[base + k] = run; run += v[k]; }
  }
}

// parallel exclusive scan over bsum (nblk <= 256 fast path; serial fallback)
__global__ __launch_bounds__(TPB) void k_scan2(
    int* __restrict__ bsum, int* __restrict__ off, int nblk, int N_, int E) {
  __shared__ int wsum[4];
  if (nblk <= TPB) {
    int t = threadIdx.x;
    int x = (t < nblk) ? bsum[t] : 0;
    int orig = x;
    const int lane = t & 63, w = t >> 6;
#pragma unroll
    for (int o = 1; o < 64; o <<= 1) {
      int y = __shfl_up(x, o, 64);
      if (lane >= o) x += y;
    }
    if (lane == 63) wsum[w] = x;
    __syncthreads();
    int add = 0;
#pragma unroll
    for (int i = 0; i < 4; ++i) add += (i < w) ? wsum[i] : 0;
    x += add;
    if (t < nblk) bsum[t] = x - orig;   // exclusive
    if (t == 0) off[N_] = E;
  } else {
    if (threadIdx.x != 0) return;
    int run = 0;
    for (int i = 0; i < nblk; ++i) { int tmp = bsum[i]; bsum[i] = run; run += tmp; }
    off[N_] = E;
  }
}

__global__ __launch_bounds__(TPB) void k_scan3(
    int* __restrict__ off, const int* __restrict__ bsum, int* __restrict__ cursor, int N_) {
  int i = blockIdx.x * blockDim.x + threadIdx.x;
  if (i >= N_) return;
  int v = off[i] + bsum[i >> 10];
  off[i] = v;
  cursor[i] = v;
}

// ---------- K12a: scatter packed {w, src} into dst-CSR order ----------
__global__ __launch_bounds__(TPB) void k_scatter0(
    const float* __restrict__ ex, const float* __restrict__ ssum,
    const int* __restrict__ src, const int* __restrict__ dst,
    int* __restrict__ cursor, float2* __restrict__ pk, int E) {
  int e = blockIdx.x * blockDim.x + threadIdx.x;
  if (e >= E) return;
  int s = src[e];
  float w = ex[e] / ssum[s];
  int pos = atomicAdd(&cursor[dst[e]], 1);
  pk[pos] = make_float2(w, __int_as_float(s));
}

// ---------- K12b: gather per dst node + 0.8/0.2 mix -> mixbuf ----------
// Zero LDS ops: pk[j] is read as a uniform global broadcast load (all 32
// lanes same address -> 1 request, L2-hot). 4 independent gathers in flight.
// Accumulation order (ascending j) unchanged -> bit-identical.
__global__ __launch_bounds__(TPB) void k_gather_mix(
    const float2* __restrict__ pk, const int* __restrict__ off,
    const float* __restrict__ repr1, float* __restrict__ mixbuf, int N_) {
  const int n = blockIdx.x * 8 + (threadIdx.x >> 5);  // node
  const int c = threadIdx.x & 31;                     // component
  if (n >= N_) return;
  const float self = repr1[(size_t)n * DD + c];
  float acc = 0.f;
  const int j0 = off[n], j1 = off[n + 1];
  int j = j0;
  for (; j + 4 <= j1; j += 4) {
    const float2 p0 = pk[j], p1 = pk[j + 1], p2 = pk[j + 2], p3 = pk[j + 3];
    const float g0 = repr1[(size_t)__float_as_int(p0.y) * DD + c];
    const float g1 = repr1[(size_t)__float_as_int(p1.y) * DD + c];
    const float g2 = repr1[(size_t)__float_as_int(p2.y) * DD + c];
    const float g3 = repr1[(size_t)__float_as_int(p3.y) * DD + c];
    acc += p0.x * g0;
    acc += p1.x * g1;
    acc += p2.x * g2;
    acc += p3.x * g3;
  }
  for (; j < j1; ++j) {
    const float2 p = pk[j];
    acc += p.x * repr1[(size_t)__float_as_int(p.y) * DD + c];
  }
  mixbuf[(size_t)n * DD + c] = 0.8f * acc + 0.2f * self;
}

// ---------- K12c: Linear + LeakyReLU (node_pre-style, SGPR weights, no shfl) ----------
// o_c = blin[c] + sum_j Wlin[c*32+j] * mix_j, ascending j -> bit-identical to
// the old fused MLP. LDS transpose tile for coalesced stores.
__global__ __launch_bounds__(TPB) void k_final_linear(
    const float* __restrict__ Wlin, const float* __restrict__ blin,
    const float* __restrict__ mixbuf, float* __restrict__ out_repr, int N_) {
  __shared__ float xp[TPB * 36];
  float4* xq = (float4*)xp;
  const int tid = threadIdx.x;
  const int nbase = blockIdx.x * TPB;
  const int n = nbase + tid;
  const int nlim = min(TPB, N_ - nbase);
  float m[32];
  if (tid < nlim) {
    const float4* h4 = (const float4*)mixbuf + (size_t)n * 8;
#pragma unroll
    for (int jq = 0; jq < 8; ++jq) {
      float4 x = h4[jq];
      m[4 * jq] = x.x; m[4 * jq + 1] = x.y; m[4 * jq + 2] = x.z; m[4 * jq + 3] = x.w;
    }
  } else {
#pragma unroll
    for (int j = 0; j < 32; ++j) m[j] = 0.f;
  }
  for (int tt = 0; tt < 4; ++tt) {
    const int c0 = tt * 8;
    float a0 = blin[c0 + 0], a1 = blin[c0 + 1], a2 = blin[c0 + 2], a3 = blin[c0 + 3];
    float a4 = blin[c0 + 4], a5 = blin[c0 + 5], a6 = blin[c0 + 6], a7 = blin[c0 + 7];
#pragma unroll
    for (int j = 0; j < 32; ++j) {
      const float hj = m[j];
      a0 += Wlin[(c0 + 0) * DD + j] * hj; a1 += Wlin[(c0 + 1) * DD + j] * hj;
      a2 += Wlin[(c0 + 2) * DD + j] * hj; a3 += Wlin[(c0 + 3) * DD + j] * hj;
      a4 += Wlin[(c0 + 4) * DD + j] * hj; a5 += Wlin[(c0 + 5) * DD + j] * hj;
      a6 += Wlin[(c0 + 6) * DD + j] * hj; a7 += Wlin[(c0 + 7) * DD + j] * hj;
    }
    a0 = (a0 >= 0.f) ? a0 : 0.01f * a0; a1 = (a1 >= 0.f) ? a1 : 0.01f * a1;
    a2 = (a2 >= 0.f) ? a2 : 0.01f * a2; a3 = (a3 >= 0.f) ? a3 : 0.01f * a3;
    a4 = (a4 >= 0.f) ? a4 : 0.01f * a4; a5 = (a5 >= 0.f) ? a5 : 0.01f * a5;
    a6 = (a6 >= 0.f) ? a6 : 0.01f * a6; a7 = (a7 >= 0.f) ? a7 : 0.01f * a7;
    xq[tid * 9 + tt * 2]     = make_float4(a0, a1, a2, a3);
    xq[tid * 9 + tt * 2 + 1] = make_float4(a4, a5, a6, a7);
  }
  NP_STORE(out_repr)
}

extern "C" void kernel_launch(void* const* d_in, const int* in_sizes, int n_in,
                              void* d_out, int out_size, void* d_ws, size_t ws_size,
                              hipStream_t stream) {
  (void)n_in; (void)out_size; (void)ws_size;
  const float* score = (const float*)d_in[0];
  const float* nrepr = (const float*)d_in[1];
  const int*   eg0   = (const int*)d_in[2];
  const int*   src0  = (const int*)d_in[3];
  const int*   dst0  = (const int*)d_in[4];
  const float* rel0  = (const float*)d_in[5];
  const int*   eg1   = (const int*)d_in[6];
  const int*   src1  = (const int*)d_in[7];
  const int*   dst1  = (const int*)d_in[8];
  const float* rel1  = (const float*)d_in[9];
  const float* qemb  = (const float*)d_in[10];
  const float* remb  = (const float*)d_in[11];
  const float* Wq    = (const float*)d_in[12];
  const float* Wk    = (const float*)d_in[13];
  const float* Wlin  = (const float*)d_in[14];
  const float* blin  = (const float*)d_in[15];
  const int*   maxe  = (const int*)d_in[16];

  const int N_ = in_sizes[0];
  const int E_ = in_sizes[2];
  const int Q_ = in_sizes[10] / DD;

  char* wsc = (char*)d_ws;
  size_t off = 0;
  auto alloc = [&](size_t bytes) -> void* {
    void* p = wsc + off;
    off += (bytes + 255) & ~(size_t)255;
    return p;
  };
  double* M64  = (double*)alloc((size_t)DD4 * DD4 * 8);
  float*  M32  = (float*)alloc((size_t)DD4 * DD4 * 4);
  double* S64  = (double*)alloc((size_t)DD * DD * 8);
  float*  S32  = (float*)alloc((size_t)DD * DD * 4);
  double* p64  = (double*)alloc((size_t)Q_ * 64 * 8);
  double* pD64 = (double*)alloc((size_t)Q_ * DD * 8);
  double* c64  = (double*)alloc((size_t)Q_ * 8);
  float*  p32  = (float*)alloc((size_t)Q_ * 64 * 4);
  float*  pD32 = (float*)alloc((size_t)Q_ * DD * 4);
  float*  c32  = (float*)alloc((size_t)Q_ * 4);
  int*    qoff = (int*)alloc((size_t)(Q_ + 2) * 4);
  double* lg1  = (double*)alloc((size_t)E_ * 8);
  double* qv64 = (double*)alloc((size_t)E_ * 8);   // per-edge rel-quadratic (reused as f32 for layer 0)
  float*  w1f  = (float*)alloc((size_t)E_ * 4);
  unsigned int* tkey = (unsigned int*)alloc((size_t)E_ * 4);
  float*  w1p  = (float*)alloc((size_t)E_ * 4);
  float*  lg0  = (float*)alloc((size_t)E_ * 4);
  float*  repr1 = (float*)alloc((size_t)N_ * DD * 4);
  float*  tvec = (float*)alloc((size_t)N_ * DD * 4);   // reused: node-pre, then CSR scratch
  float*  uvec = (float*)alloc((size_t)N_ * DD * 4);   // reused: then pk
  float*  vvec = (float*)alloc((size_t)N_ * DD * 4);   // reused: then mixbuf
  // zero-initialized region (contiguous)
  size_t zstart = off;
  unsigned long long* mkey1 = (unsigned long long*)alloc((size_t)N_ * 8);
  double* s1   = (double*)alloc((size_t)N_ * 8);
  float*  agg  = (float*)alloc((size_t)N_ * DD * 4);
  unsigned int* mkey0 = (unsigned int*)alloc((size_t)N_ * 4);
  float*  s0   = (float*)alloc((size_t)N_ * 4);
  size_t zlen = off - zstart;

  float* qv32 = (float*)qv64;   // layer-0 reuse (layer-1 consumer already done)

  // CSR scratch aliases tvec (dead after k_edge_dots<float>); pk aliases uvec;
  // mixbuf aliases vvec (dead after k_edge_dots<float>).
  // NOTE padding: offcsr needs N+1 ints — cursor must start past offcsr[N].
  int* cnt    = (int*)tvec;                         // [0, N)
  int* offcsr = (int*)tvec + N_;                    // [N, 2N+1)  (N+1 ints!)
  int* cursor = (int*)tvec + 2 * (size_t)N_ + 64;   // padded past offcsr[N]
  int* bsum   = (int*)tvec + 3 * (size_t)N_ + 128;  // nblk ints
  float2* pk  = (float2*)uvec;                      // E float2 = 4 MB (uvec is 12.8 MB)
  float* mixbuf = vvec;

  float* out_score = (float*)d_out;
  float* out_repr  = out_score + N_;

  hipMemsetAsync(wsc + zstart, 0, zlen, stream);
  hipMemsetAsync(d_out, 0, (size_t)N_ * 4, stream);

  k_precompute_M<<<(DD4 * DD4) / TPB, TPB, 0, stream>>>(Wq, Wk, M64, M32);
  k_sym22<<<4, TPB, 0, stream>>>(M64, S64, S32);
  k_per_query<<<Q_, 64, 0, stream>>>(M64, qemb, remb, p64, pD64, c64, p32, pD32, c32);

  const int ngrid = (N_ + TPB - 1) / TPB;
  const int egrid = (E_ + TPB - 1) / TPB;
  const int dgrid1 = (int)(((size_t)E_ * 8 + TPB - 1) / TPB);
  const int dgrid2 = (int)(((size_t)((E_ + 1) / 2) * 8 + TPB - 1) / TPB);

  // ---- layer 1 (f64 logits path, selection-critical) ----
  k_node_pre<double, false><<<ngrid, TPB, 0, stream>>>(M64, nrepr, nullptr, nullptr,
                                                       tvec, uvec, vvec, N_);
  k_quad<double><<<egrid, TPB, 0, stream>>>(S64, rel1, eg1, p64, c64, qv64, E_);
  k_edge_dots<double><<<dgrid2, TPB, 0, stream>>>(nrepr, rel1, src1, dst1, eg1,
                                                  tvec, uvec, vvec, p64, pD64, qv64,
                                                  lg1, (void*)mkey1, E_);
  k_expsum64<<<egrid, TPB, 0, stream>>>(lg1, mkey1, src1, s1, E_);
  k_weights_target<<<egrid, TPB, 0, stream>>>(lg1, s1, src1, score, eg1, qoff,
                                              w1f, tkey, E_, Q_);
  k_topk<<<Q_, TPB, 0, stream>>>(tkey, w1f, qoff, maxe, w1p, E_);

  k_apply1<<<dgrid1, TPB, 0, stream>>>(w1p, src1, dst1, nrepr, score, agg, out_score, E_);

  // ---- layer 0 (f32): node-pre fused with the 0.8/0.2 mix ----
  k_node_pre<float, true><<<ngrid, TPB, 0, stream>>>(M32, nrepr, agg, repr1,
                                                     tvec, uvec, vvec, N_);
  k_quad<float><<<egrid, TPB, 0, stream>>>(S32, rel0, eg0, p32, c32, qv32, E_);
  k_edge_dots<float><<<dgrid2, TPB, 0, stream>>>(repr1, rel0, src0, dst0, eg0,
                                                 tvec, uvec, vvec, p32, pD32, qv32,
                                                 lg0, (void*)mkey0, E_);

  // ---- CSR build (tvec/uvec/vvec dead after k_edge_dots<float>) ----
  hipMemsetAsync(cnt, 0, (size_t)N_ * 4, stream);
  k_expsum32h<<<egrid, TPB, 0, stream>>>(lg0, mkey0, src0, dst0, s0, cnt, E_);
  const int nblk = (N_ + SCHUNK - 1) / SCHUNK;
  k_scan1<<<nblk, TPB, 0, stream>>>(cnt, offcsr, bsum, N_);
  k_scan2<<<1, TPB, 0, stream>>>(bsum, offcsr, nblk, N_, E_);
  k_scan3<<<ngrid, TPB, 0, stream>>>(offcsr, bsum, cursor, N_);
  k_scatter0<<<egrid, TPB, 0, stream>>>(lg0, s0, src0, dst0, cursor, pk, E_);
  k_gather_mix<<<(N_ + 7) / 8, TPB, 0, stream>>>(pk, offcsr, repr1, mixbuf, N_);
  k_final_linear<<<ngrid, TPB, 0, stream>>>(Wlin, blin, mixbuf, out_repr, N_);
}